// Round 1
// baseline (67374.146 us; speedup 1.0000x reference)
//
#include <hip/hip_runtime.h>
#include <hip/hip_bf16.h>
#include <stdint.h>

// Seq2Seq w/ attention, MI355X. Structure:
//  K0: fold G=Wq^T Wk, N=attn_out_w*Wv (+bias folds), zero h-state & barrier counters.
//  K1: encoder. 4 groups x 64 blocks; block owns 8 hidden units (32 z-rows) for 16 batches,
//      Whh slice LDS-resident; per-step h-exchange via global + custom 64-block barrier.
//  K2: decoder. Same cell partition + 7 barrier-phases/step:
//      cell -> htilde=G*h -> scores/softmax-partials/ebar-partials (flash-style, enc_out bf16)
//      -> combine ebar -> ctx=N*ebar + y + LN-stats -> LN+out partial -> final out (autoregressive x).

#define HID 512
#define NBAT 64
#define SEQE 512
#define SEQD 128
#define NGRP 4
#define GBAT 16
#define GBLK 64
#define NH 8
#define NR 32
#define LDP 516   // padded LDS row (stride%32 == 4 banks -> conflict-free patterns)
#define SCALE 0.04419417382415922f

static constexpr size_t OFF_G   = 0;
static constexpr size_t OFF_NM  = OFF_G  + (size_t)HID*HID*4;
static constexpr size_t OFF_M0  = OFF_NM + (size_t)HID*HID*4;
static constexpr size_t OFF_N0  = OFF_M0 + (size_t)HID*4;
static constexpr size_t OFF_HB  = OFF_N0 + (size_t)HID*4;          // h double buffer [2][B][H] f32
static constexpr size_t OFF_CB  = OFF_HB + (size_t)2*NBAT*HID*4;   // c handoff [B][H]
static constexpr size_t OFF_XC  = OFF_CB + (size_t)NBAT*HID*4;     // x feedback [B]
static constexpr size_t OFF_HT  = OFF_XC + 256;                    // htilde [B][H]
static constexpr size_t OFF_EBP = OFF_HT + (size_t)NBAT*HID*4;     // ebar partials [B][4][H]
static constexpr size_t OFF_MD  = OFF_EBP + (size_t)NBAT*4*HID*4;  // (m,d) [B][4][2]
static constexpr size_t OFF_EBC = OFF_MD + (size_t)NBAT*8*4;       // ebar combined [B][H]
static constexpr size_t OFF_LNS = OFF_EBC + (size_t)NBAT*HID*4;    // LN stats [G][64][16][2]
static constexpr size_t OFF_OP  = OFF_LNS + (size_t)NGRP*GBLK*GBAT*2*4; // out partials [G][64][16]
static constexpr size_t OFF_CNT = OFF_OP + (size_t)NGRP*GBLK*GBAT*4;    // 16 barrier counters
static constexpr size_t OFF_EO  = ((OFF_CNT + 64 + 255) & ~(size_t)255); // enc_out bf16 [B][Se][H]

__device__ __forceinline__ float bf2f(uint32_t u) {
  union { float f; uint32_t i; } x; x.i = u << 16; return x.f;
}
__device__ __forceinline__ float sigm(float x) { return 1.f / (1.f + __expf(-x)); }

// 64-block group barrier: release fence by every thread, one monotonic counter per group.
__device__ __forceinline__ void gbar(int* cnt, int& epoch) {
  __threadfence();
  __syncthreads();
  if (threadIdx.x == 0) {
    epoch++;
    atomicAdd(cnt, 1);
    const int tgt = GBLK * epoch;
    while (__hip_atomic_load(cnt, __ATOMIC_RELAXED, __HIP_MEMORY_SCOPE_AGENT) < tgt)
      __builtin_amdgcn_s_sleep(4);
  }
  __syncthreads();
  __threadfence();  // acquire: invalidate L1 so remote writes are seen
}

__global__ __launch_bounds__(256) void k0_prep(
    const float* __restrict__ aiw, const float* __restrict__ aib,
    const float* __restrict__ aow, const float* __restrict__ aob,
    char* __restrict__ ws) {
  float* Gm = (float*)(ws + OFF_G);
  float* Nm = (float*)(ws + OFF_NM);
  float* m0 = (float*)(ws + OFF_M0);
  float* n0 = (float*)(ws + OFF_N0);
  const int blk = blockIdx.x, tid = threadIdx.x;
  if (blk == 512) {
    float* hb = (float*)(ws + OFF_HB);
    for (int i = tid; i < NBAT*HID; i += 256) hb[i] = 0.f;   // h0 = 0 (slot 0)
    if (tid < 16) ((int*)(ws + OFF_CNT))[tid] = 0;           // re-zero every launch (replay-safe)
    for (int l = tid; l < HID; l += 256) {
      float s = 0.f;
      for (int i = 0; i < HID; i++) s += aib[i] * aiw[(size_t)(HID + i)*HID + l];
      m0[l] = s;  // Wk^T bq
    }
    for (int j = tid; j < HID; j += 256) {
      float s = aob[j];
      for (int i = 0; i < HID; i++) s += aow[(size_t)j*HID + i] * aib[2*HID + i];
      n0[j] = s;  // aow*bv + aob
    }
    return;
  }
  const bool isG = blk < 256;
  const int tb = isG ? blk : blk - 256;
  const int r0 = (tb >> 4) * 32, c0 = (tb & 15) * 32;
  __shared__ float sa[32][33], sb[32][33];
  float acc[4] = {0.f, 0.f, 0.f, 0.f};
  const int tr = tid >> 3, tc = (tid & 7) * 4;
  for (int i0 = 0; i0 < HID; i0 += 32) {
    __syncthreads();
    if (isG) {  // G[l][k] = sum_i Wk[i][l]*Wq[i][k]
      for (int j = 0; j < 4; j++) sa[tr][tc + j] = aiw[(size_t)(HID + i0 + tr)*HID + r0 + tc + j];
      for (int j = 0; j < 4; j++) sb[tr][tc + j] = aiw[(size_t)(i0 + tr)*HID + c0 + tc + j];
    } else {    // N[j][l] = sum_i aow[j][i]*Wv[i][l]
      for (int j = 0; j < 4; j++) sa[tr][tc + j] = aow[(size_t)(r0 + tr)*HID + i0 + tc + j];
      for (int j = 0; j < 4; j++) sb[tr][tc + j] = aiw[(size_t)(2*HID + i0 + tr)*HID + c0 + tc + j];
    }
    __syncthreads();
    if (isG) {
      for (int i = 0; i < 32; i++) {
        float a = sa[i][tr];
        for (int j = 0; j < 4; j++) acc[j] += a * sb[i][tc + j];
      }
    } else {
      for (int i = 0; i < 32; i++) {
        float a = sa[tr][i];
        for (int j = 0; j < 4; j++) acc[j] += a * sb[i][tc + j];
      }
    }
  }
  float* dst = isG ? Gm : Nm;
  for (int j = 0; j < 4; j++) dst[(size_t)(r0 + tr)*HID + c0 + tc + j] = acc[j];
}

// ---- shared cell-compute macro body (z = Whh_slice * h + x*wih + bias), 4x4 reg tiles ----
#define CELL_Z_COMPUTE()                                                          \
  {                                                                               \
    float acc[4][4];                                                              \
    _Pragma("unroll") for (int a = 0; a < 4; a++)                                 \
      _Pragma("unroll") for (int b = 0; b < 4; b++) acc[a][b] = 0.f;              \
    const int p0 = kc * 32;                                                       \
    _Pragma("unroll 2") for (int p = p0; p < p0 + 32; p++) {                      \
      float2 w0 = *(const float2*)&s_w[rg*4+0][2*p];                              \
      float2 w1 = *(const float2*)&s_w[rg*4+1][2*p];                              \
      float2 w2 = *(const float2*)&s_w[rg*4+2][2*p];                              \
      float2 w3 = *(const float2*)&s_w[rg*4+3][2*p];                              \
      float2 h0 = *(const float2*)&s_h[bg*4+0][2*p];                              \
      float2 h1 = *(const float2*)&s_h[bg*4+1][2*p];                              \
      float2 h2 = *(const float2*)&s_h[bg*4+2][2*p];                              \
      float2 h3 = *(const float2*)&s_h[bg*4+3][2*p];                              \
      acc[0][0] += w0.x*h0.x + w0.y*h0.y; acc[0][1] += w0.x*h1.x + w0.y*h1.y;     \
      acc[0][2] += w0.x*h2.x + w0.y*h2.y; acc[0][3] += w0.x*h3.x + w0.y*h3.y;     \
      acc[1][0] += w1.x*h0.x + w1.y*h0.y; acc[1][1] += w1.x*h1.x + w1.y*h1.y;     \
      acc[1][2] += w1.x*h2.x + w1.y*h2.y; acc[1][3] += w1.x*h3.x + w1.y*h3.y;     \
      acc[2][0] += w2.x*h0.x + w2.y*h0.y; acc[2][1] += w2.x*h1.x + w2.y*h1.y;     \
      acc[2][2] += w2.x*h2.x + w2.y*h2.y; acc[2][3] += w2.x*h3.x + w2.y*h3.y;     \
      acc[3][0] += w3.x*h0.x + w3.y*h0.y; acc[3][1] += w3.x*h1.x + w3.y*h1.y;     \
      acc[3][2] += w3.x*h2.x + w3.y*h2.y; acc[3][3] += w3.x*h3.x + w3.y*h3.y;     \
    }                                                                             \
    _Pragma("unroll") for (int a = 0; a < 4; a++)                                 \
      _Pragma("unroll") for (int b = 0; b < 4; b++)                               \
        s_part[kc*512 + (rg*4+a)*GBAT + bg*4 + b] = acc[a][b];                    \
  }                                                                               \
  __syncthreads();                                                                \
  for (int o = tid; o < NR*GBAT; o += 256) {                                      \
    float s = 0.f;                                                                \
    _Pragma("unroll") for (int c = 0; c < 8; c++) s += s_part[c*512 + o];         \
    int r = o >> 4, bb = o & 15;                                                  \
    s_z[o] = s + s_x[bb]*s_wih[r] + s_bias[r];                                    \
  }                                                                               \
  __syncthreads();

#define STAGE_GROUP(dstLDS, srcPTR)                                               \
  {                                                                               \
    const float4* _src = (const float4*)(srcPTR);                                 \
    for (int i = tid; i < GBAT*HID/4; i += 256) {                                 \
      float4 v = _src[i];                                                         \
      int bb = i >> 7, kk = (i & 127) * 4;                                        \
      dstLDS[bb][kk] = v.x; dstLDS[bb][kk+1] = v.y;                               \
      dstLDS[bb][kk+2] = v.z; dstLDS[bb][kk+3] = v.w;                             \
    }                                                                             \
  }

__global__ __launch_bounds__(256) void k1_enc(
    const float* __restrict__ xin, const float* __restrict__ wih,
    const float* __restrict__ whh, const float* __restrict__ bih,
    const float* __restrict__ bhh, char* __restrict__ ws) {
  const int bk = blockIdx.x, tid = threadIdx.x;
  const int g = bk >> 6, jb = bk & 63;
  const int hs = jb * NH, b0 = g * GBAT;
  float* hbuf = (float*)(ws + OFF_HB);
  float* cbuf = (float*)(ws + OFF_CB);
  __hip_bfloat16* eo = (__hip_bfloat16*)(ws + OFF_EO);
  int* cnt = (int*)(ws + OFF_CNT) + g;

  __shared__ float s_w[NR][LDP];
  __shared__ float s_h[GBAT][LDP];
  __shared__ float s_part[8*512];
  __shared__ float s_z[NR*GBAT];
  __shared__ float s_c[GBAT][NH];
  __shared__ float s_x[GBAT];
  __shared__ float s_wih[NR], s_bias[NR];

  for (int r = 0; r < NR; r++) {
    int grow = (r >> 3)*HID + hs + (r & 7);
    for (int k = tid; k < HID; k += 256) s_w[r][k] = whh[(size_t)grow*HID + k];
  }
  if (tid < NR) {
    int grow = (tid >> 3)*HID + hs + (tid & 7);
    s_wih[tid] = wih[grow];
    s_bias[tid] = bih[grow] + bhh[grow];
  }
  for (int i = tid; i < GBAT*NH; i += 256) s_c[i >> 3][i & 7] = 0.f;

  const int rg = tid & 7, bg = (tid >> 3) & 3, kc = tid >> 5;
  int epoch = 0;
  for (int t = 0; t < SEQE; t++) {
    STAGE_GROUP(s_h, hbuf + (size_t)(t & 1)*NBAT*HID + (size_t)b0*HID)
    if (tid < GBAT) s_x[tid] = xin[(size_t)(b0 + tid)*SEQE + t];
    __syncthreads();
    CELL_Z_COMPUTE()
    if (tid < GBAT*NH) {
      int bb = tid >> 3, jj = tid & 7;
      float zi = s_z[(jj)*GBAT + bb];
      float zf = s_z[(8+jj)*GBAT + bb];
      float zg = s_z[(16+jj)*GBAT + bb];
      float zo = s_z[(24+jj)*GBAT + bb];
      float c = s_c[bb][jj];
      c = sigm(zf)*c + sigm(zi)*tanhf(zg);
      float hv = sigm(zo)*tanhf(c);
      s_c[bb][jj] = c;
      hbuf[(size_t)((t+1)&1)*NBAT*HID + (size_t)(b0+bb)*HID + hs + jj] = hv;
      eo[((size_t)(b0+bb)*SEQE + t)*HID + hs + jj] = __float2bfloat16(hv);
    }
    gbar(cnt, epoch);
  }
  if (tid < GBAT*NH) {
    int bb = tid >> 3, jj = tid & 7;
    cbuf[(size_t)(b0+bb)*HID + hs + jj] = s_c[bb][jj];
  }
}

__global__ __launch_bounds__(256) void k2_dec(
    const float* __restrict__ xin, const float* __restrict__ wih,
    const float* __restrict__ whh, const float* __restrict__ bih,
    const float* __restrict__ bhh, const float* __restrict__ lng,
    const float* __restrict__ lnb, const float* __restrict__ outw,
    const float* __restrict__ outb, char* __restrict__ ws,
    float* __restrict__ dout) {
  const int bk = blockIdx.x, tid = threadIdx.x;
  const int g = bk >> 6, jb = bk & 63;
  const int hs = jb * NH, b0 = g * GBAT;
  float* hbuf = (float*)(ws + OFF_HB);
  float* cbuf = (float*)(ws + OFF_CB);
  float* xcur = (float*)(ws + OFF_XC);
  float* htil = (float*)(ws + OFF_HT);
  float* ebp  = (float*)(ws + OFF_EBP);
  float* md   = (float*)(ws + OFF_MD);
  float* ebc  = (float*)(ws + OFF_EBC);
  float* lns  = (float*)(ws + OFF_LNS);
  float* outp = (float*)(ws + OFF_OP);
  const float* Gm  = (const float*)(ws + OFF_G);
  const float* Nm  = (const float*)(ws + OFF_NM);
  const float* m0v = (const float*)(ws + OFF_M0);
  const float* n0v = (const float*)(ws + OFF_N0);
  const __hip_bfloat16* eo = (const __hip_bfloat16*)(ws + OFF_EO);
  int* cnt = (int*)(ws + OFF_CNT) + 4 + g;

  __shared__ float s_w[NR][LDP];
  __shared__ float s_h[GBAT][LDP];
  __shared__ float s_part[8*512];
  __shared__ float s_z[NR*GBAT];
  __shared__ float s_c[GBAT][NH];
  __shared__ float s_hown[GBAT][NH];
  __shared__ float s_x[GBAT];
  __shared__ float s_wih[NR], s_bias[NR];
  __shared__ float s_ht[HID];
  __shared__ float s_scores[128];
  __shared__ float s_sc2[256];
  __shared__ float s_red[256];
  __shared__ float2 s_f2[256];
  __shared__ float s_mu[GBAT], s_rs[GBAT];

  for (int r = 0; r < NR; r++) {
    int grow = (r >> 3)*HID + hs + (r & 7);
    for (int k = tid; k < HID; k += 256) s_w[r][k] = whh[(size_t)grow*HID + k];
  }
  if (tid < NR) {
    int grow = (tid >> 3)*HID + hs + (tid & 7);
    s_wih[tid] = wih[grow];
    s_bias[tid] = bih[grow] + bhh[grow];
  }
  for (int i = tid; i < GBAT*NH; i += 256) {
    int bb = i >> 3, jj = i & 7;
    s_c[bb][jj] = cbuf[(size_t)(b0+bb)*HID + hs + jj];
  }

  const int rg = tid & 7, bg = (tid >> 3) & 3, kc = tid >> 5;
  const int l8 = tid >> 5, kq = tid & 31;
  int epoch = 0;
  for (int t = 0; t < SEQD; t++) {
    // ---------- P1: LSTM cell ----------
    STAGE_GROUP(s_h, hbuf + (size_t)(t & 1)*NBAT*HID + (size_t)b0*HID)
    if (tid < GBAT) s_x[tid] = (t == 0) ? xin[(size_t)(b0 + tid)*SEQD] : xcur[b0 + tid];
    __syncthreads();
    CELL_Z_COMPUTE()
    if (tid < GBAT*NH) {
      int bb = tid >> 3, jj = tid & 7;
      float zi = s_z[(jj)*GBAT + bb];
      float zf = s_z[(8+jj)*GBAT + bb];
      float zg = s_z[(16+jj)*GBAT + bb];
      float zo = s_z[(24+jj)*GBAT + bb];
      float c = s_c[bb][jj];
      c = sigm(zf)*c + sigm(zi)*tanhf(zg);
      float hv = sigm(zo)*tanhf(c);
      s_c[bb][jj] = c;
      s_hown[bb][jj] = hv;
      hbuf[(size_t)((t+1)&1)*NBAT*HID + (size_t)(b0+bb)*HID + hs + jj] = hv;
    }
    gbar(cnt, epoch);  // B1
    // ---------- P2: htilde = G*h_new + m0 ----------
    STAGE_GROUP(s_h, hbuf + (size_t)((t+1) & 1)*NBAT*HID + (size_t)b0*HID)
    __syncthreads();
    {
      float pacc[GBAT];
      #pragma unroll
      for (int b = 0; b < GBAT; b++) pacc[b] = 0.f;
      const float2* Gr = (const float2*)(Gm + (size_t)(hs + l8)*HID);
      for (int kk2 = 0; kk2 < 8; kk2++) {
        int p = kk2*32 + kq;
        float2 gv = Gr[p];
        #pragma unroll
        for (int b = 0; b < GBAT; b++) {
          float2 hv2 = *(const float2*)&s_h[b][2*p];
          pacc[b] += gv.x*hv2.x + gv.y*hv2.y;
        }
      }
      #pragma unroll
      for (int b = 0; b < GBAT; b++) s_part[(l8*32 + kq)*GBAT + b] = pacc[b];
    }
    __syncthreads();
    if (tid < NH*GBAT) {
      int l = tid >> 4, b = tid & 15;
      float s = m0v[hs + l];
      for (int q = 0; q < 32; q++) s += s_part[(l*32 + q)*GBAT + b];
      htil[(size_t)(b0+b)*HID + hs + l] = s;
    }
    gbar(cnt, epoch);  // B2
    // ---------- P3: scores + local softmax + ebar partial (flash-style) ----------
    {
      const int bb = jb >> 2, sc = jb & 3;
      const int batch = b0 + bb;
      for (int i = tid; i < HID; i += 256) s_ht[i] = htil[(size_t)batch*HID + i];
      __syncthreads();
      const int sidx = tid >> 1, half = tid & 1;
      const uint4* ep = (const uint4*)(eo + ((size_t)batch*SEQE + sc*128 + sidx)*HID + half*256);
      float acc = 0.f;
      const int lb = half * 256;
      #pragma unroll 4
      for (int it = 0; it < 32; it++) {
        uint4 u = ep[it];
        int l = lb + it*8;
        acc += bf2f(u.x & 0xffffu)*s_ht[l+0] + bf2f(u.x >> 16)*s_ht[l+1]
             + bf2f(u.y & 0xffffu)*s_ht[l+2] + bf2f(u.y >> 16)*s_ht[l+3]
             + bf2f(u.z & 0xffffu)*s_ht[l+4] + bf2f(u.z >> 16)*s_ht[l+5]
             + bf2f(u.w & 0xffffu)*s_ht[l+6] + bf2f(u.w >> 16)*s_ht[l+7];
      }
      s_sc2[tid] = acc;
      __syncthreads();
      float lg = -1e30f;
      if (tid < 128) { lg = (s_sc2[tid*2] + s_sc2[tid*2+1]) * SCALE; s_scores[tid] = lg; }
      s_red[tid] = lg;
      __syncthreads();
      for (int st = 128; st > 0; st >>= 1) {
        if (tid < st) s_red[tid] = fmaxf(s_red[tid], s_red[tid + st]);
        __syncthreads();
      }
      const float ml = s_red[0];
      __syncthreads();
      float pv = 0.f;
      if (tid < 128) { pv = __expf(s_scores[tid] - ml); s_scores[tid] = pv; }
      s_red[tid] = pv;
      __syncthreads();
      for (int st = 128; st > 0; st >>= 1) {
        if (tid < st) s_red[tid] += s_red[tid + st];
        __syncthreads();
      }
      const float dl = s_red[0];
      float a0 = 0.f, a1 = 0.f;
      const uint32_t* ep2 = (const uint32_t*)(eo + ((size_t)batch*SEQE + sc*128)*HID);
      for (int s = 0; s < 128; s++) {
        float p = s_scores[s];
        uint32_t u = ep2[(size_t)s*(HID/2) + tid];
        a0 += p * bf2f(u & 0xffffu);
        a1 += p * bf2f(u >> 16);
      }
      ((float2*)(ebp + (size_t)(batch*4 + sc)*HID))[tid] = make_float2(a0, a1);
      if (tid == 0) { md[(batch*4 + sc)*2] = ml; md[(batch*4 + sc)*2 + 1] = dl; }
    }
    gbar(cnt, epoch);  // B3
    // ---------- P4: combine ebar across 4 Se-chunks ----------
    {
      const int bb = jb >> 2, lc = jb & 3;
      const int batch = b0 + bb;
      float mm0 = md[batch*8+0], dd0 = md[batch*8+1];
      float mm1 = md[batch*8+2], dd1 = md[batch*8+3];
      float mm2 = md[batch*8+4], dd2 = md[batch*8+5];
      float mm3 = md[batch*8+6], dd3 = md[batch*8+7];
      float M = fmaxf(fmaxf(mm0, mm1), fmaxf(mm2, mm3));
      float w0 = __expf(mm0 - M), w1 = __expf(mm1 - M);
      float w2 = __expf(mm2 - M), w3 = __expf(mm3 - M);
      float inv = 1.f / (w0*dd0 + w1*dd1 + w2*dd2 + w3*dd3);
      if (tid < 128) {
        int l = lc*128 + tid;
        float v = w0*ebp[(size_t)(batch*4+0)*HID + l] + w1*ebp[(size_t)(batch*4+1)*HID + l]
                + w2*ebp[(size_t)(batch*4+2)*HID + l] + w3*ebp[(size_t)(batch*4+3)*HID + l];
        ebc[(size_t)batch*HID + l] = v * inv;
      }
    }
    gbar(cnt, epoch);  // B4
    // ---------- P5: ctx = N*ebar + n0; y = ctx + h; LN partial stats ----------
    STAGE_GROUP(s_h, ebc + (size_t)b0*HID)
    __syncthreads();
    {
      float pacc[GBAT];
      #pragma unroll
      for (int b = 0; b < GBAT; b++) pacc[b] = 0.f;
      const float2* Nr = (const float2*)(Nm + (size_t)(hs + l8)*HID);
      for (int kk2 = 0; kk2 < 8; kk2++) {
        int p = kk2*32 + kq;
        float2 nv = Nr[p];
        #pragma unroll
        for (int b = 0; b < GBAT; b++) {
          float2 hv2 = *(const float2*)&s_h[b][2*p];
          pacc[b] += nv.x*hv2.x + nv.y*hv2.y;
        }
      }
      #pragma unroll
      for (int b = 0; b < GBAT; b++) s_part[(l8*32 + kq)*GBAT + b] = pacc[b];
    }
    __syncthreads();
    if (tid < NH*GBAT) {
      int l = tid >> 4, b = tid & 15;
      float s = n0v[hs + l];
      for (int q = 0; q < 32; q++) s += s_part[(l*32 + q)*GBAT + b];
      float y = s + s_hown[b][l];
      s_z[l*GBAT + b] = y;
    }
    __syncthreads();
    if (tid < GBAT) {
      float sy = 0.f, sy2 = 0.f;
      for (int l = 0; l < NH; l++) { float y = s_z[l*GBAT + tid]; sy += y; sy2 += y*y; }
      float* pp = lns + ((size_t)(g*GBLK + jb)*GBAT + tid)*2;
      pp[0] = sy; pp[1] = sy2;
    }
    gbar(cnt, epoch);  // B5
    // ---------- P6: LN finalize + out partial ----------
    {
      const int b = tid & 15, q = tid >> 4;
      float sy = 0.f, sy2 = 0.f;
      for (int r = 0; r < 4; r++) {
        const float* pp = lns + ((size_t)(g*GBLK + q*4 + r)*GBAT + b)*2;
        sy += pp[0]; sy2 += pp[1];
      }
      s_f2[tid] = make_float2(sy, sy2);
      __syncthreads();
      for (int st = 128; st >= 16; st >>= 1) {
        if (tid < st) { s_f2[tid].x += s_f2[tid + st].x; s_f2[tid].y += s_f2[tid + st].y; }
        __syncthreads();
      }
      if (tid < GBAT) {
        float mu = s_f2[tid].x * (1.f/HID);
        float var = s_f2[tid].y * (1.f/HID) - mu*mu;
        s_mu[tid] = mu;
        s_rs[tid] = rsqrtf(var + 1e-5f);
      }
      __syncthreads();
      float po = 0.f;
      if (tid < 128) {
        int l = tid >> 4, b2 = tid & 15;
        float y = s_z[l*GBAT + b2];
        float yh = (y - s_mu[b2]) * s_rs[b2] * lng[hs + l] + lnb[hs + l];
        po = yh * outw[hs + l];
      }
      s_red[tid] = po;
      __syncthreads();
      for (int st = 64; st >= 16; st >>= 1) {
        if (tid < st) s_red[tid] += s_red[tid + st];
        __syncthreads();
      }
      if (tid < GBAT) outp[(size_t)(g*GBLK + jb)*GBAT + tid] = s_red[tid];
    }
    gbar(cnt, epoch);  // B6
    // ---------- P7: final out + autoregressive feedback ----------
    if ((jb & 3) == 0) {
      const int bb = jb >> 2;
      const int batch = b0 + bb;
      float v = (tid < GBLK) ? outp[(size_t)(g*GBLK + tid)*GBAT + bb] : 0.f;
      if (tid < 64) {
        for (int off = 32; off > 0; off >>= 1) v += __shfl_down(v, off);
      }
      if (tid == 0) {
        float o = v + outb[0];
        dout[(size_t)batch*SEQD + t] = o;
        xcur[batch] = o;
      }
    }
    gbar(cnt, epoch);  // B7
  }
}

extern "C" void kernel_launch(void* const* d_in, const int* in_sizes, int n_in,
                              void* d_out, int out_size, void* d_ws, size_t ws_size,
                              hipStream_t stream) {
  const float* enc_in = (const float*)d_in[0];
  const float* dec_in = (const float*)d_in[1];
  const float* ewih = (const float*)d_in[2];
  const float* ewhh = (const float*)d_in[3];
  const float* ebih = (const float*)d_in[4];
  const float* ebhh = (const float*)d_in[5];
  const float* dwih = (const float*)d_in[6];
  const float* dwhh = (const float*)d_in[7];
  const float* dbih = (const float*)d_in[8];
  const float* dbhh = (const float*)d_in[9];
  const float* aiw  = (const float*)d_in[10];
  const float* aib  = (const float*)d_in[11];
  const float* aow  = (const float*)d_in[12];
  const float* aob  = (const float*)d_in[13];
  const float* lng  = (const float*)d_in[14];
  const float* lnb  = (const float*)d_in[15];
  const float* outw = (const float*)d_in[16];
  const float* outb = (const float*)d_in[17];
  char* ws = (char*)d_ws;
  k0_prep<<<513, 256, 0, stream>>>(aiw, aib, aow, aob, ws);
  k1_enc<<<256, 256, 0, stream>>>(enc_in, ewih, ewhh, ebih, ebhh, ws);
  k2_dec<<<256, 256, 0, stream>>>(dec_in, dwih, dwhh, dbih, dbhh,
                                  lng, lnb, outw, outb, ws, (float*)d_out);
}

// Round 2
// 11273.248 us; speedup vs baseline: 5.9765x; 5.9765x over previous
//
#include <hip/hip_runtime.h>
#include <hip/hip_bf16.h>
#include <stdint.h>

// Seq2Seq w/ attention, MI355X.
//  K0: fold G=Wq^T Wk, N=attn_out_w*Wv, bias folds, Swg/Swb scalars; zero h0/flags.
//  K1: encoder. 4 groups x 64 blocks, Whh slice LDS-resident, 1 flag-barrier/step.
//  K2: decoder. 6 flag-barriers/step:
//      B1 h -> B2 htilde(G slice in LDS) -> B3 score/softmax/ebar partials ->
//      B4 ebar combine -> B5 ctx(N slice in LDS)+y+LN partials -> B6 out+xcur.
// Cross-block mutable data: agent-scope RELAXED atomics (sc1 path, coherence at IF,
// NO cache flushes). Read-only data (Whh,G,N,eo): normal cached loads.

#define HID 512
#define NBAT 64
#define SEQE 512
#define SEQD 128
#define NGRP 4
#define GBAT 16
#define GBLK 64
#define NH 8
#define NR 32
#define LDP 516
#define SCALE 0.04419417382415922f
#define FLS 16  // flag stride (ints) = 64B line

static constexpr size_t OFF_G   = 0;
static constexpr size_t OFF_NM  = OFF_G  + (size_t)HID*HID*4;
static constexpr size_t OFF_M0  = OFF_NM + (size_t)HID*HID*4;
static constexpr size_t OFF_N0  = OFF_M0 + 2048;
static constexpr size_t OFF_SC  = OFF_N0 + 2048;                    // Swg, Swb
static constexpr size_t OFF_HB  = OFF_SC + 256;                     // h dbuf [2][B][H]
static constexpr size_t OFF_CB  = OFF_HB + (size_t)2*NBAT*HID*4;    // c handoff
static constexpr size_t OFF_XC  = OFF_CB + (size_t)NBAT*HID*4;      // x feedback
static constexpr size_t OFF_HT  = OFF_XC + 256;                     // htilde [B][H]
static constexpr size_t OFF_EBP = OFF_HT + (size_t)NBAT*HID*4;      // ebar partials [B][4][H]
static constexpr size_t OFF_MD  = OFF_EBP + (size_t)NBAT*4*HID*4;   // (m,d) [B][4][2]
static constexpr size_t OFF_EBC = OFF_MD + (size_t)NBAT*8*4;        // ebar combined [B][H]
static constexpr size_t OFF_LNS = OFF_EBC + (size_t)NBAT*HID*4;     // [G][64][16][4]: sy,sy2,swgy
static constexpr size_t OFF_FLG = OFF_LNS + (size_t)NGRP*GBLK*GBAT*4*4;  // 2 sets x 4 x 64 flags
static constexpr size_t OFF_EO  = ((OFF_FLG + (size_t)2*NGRP*GBLK*FLS*4 + 255) & ~(size_t)255);

__device__ __forceinline__ float bf2f(uint32_t u) {
  union { float f; uint32_t i; } x; x.i = u << 16; return x.f;
}
__device__ __forceinline__ float sigm(float x) { return 1.f / (1.f + __expf(-x)); }

__device__ __forceinline__ void stg(float* p, float v) {
  __hip_atomic_store(p, v, __ATOMIC_RELAXED, __HIP_MEMORY_SCOPE_AGENT);
}
__device__ __forceinline__ float ldg1(const float* p) {
  return __hip_atomic_load((float*)p, __ATOMIC_RELAXED, __HIP_MEMORY_SCOPE_AGENT);
}
__device__ __forceinline__ unsigned long long ldg8(const void* p) {
  return __hip_atomic_load((unsigned long long*)p, __ATOMIC_RELAXED, __HIP_MEMORY_SCOPE_AGENT);
}

// fence-free 64-block barrier: per-block padded flag, epoch protocol.
// __syncthreads() drains vmcnt of every wave (HIP emits s_waitcnt vmcnt(0) before
// s_barrier), so sc1 data stores are at the coherence point before the flag store.
__device__ __forceinline__ void gbar(int* fl, int jb, int& epoch) {
  __syncthreads();
  epoch++;
  if (threadIdx.x == 0)
    __hip_atomic_store(&fl[jb * FLS], epoch, __ATOMIC_RELAXED, __HIP_MEMORY_SCOPE_AGENT);
  if (threadIdx.x < GBLK) {
    while (__hip_atomic_load(&fl[threadIdx.x * FLS], __ATOMIC_RELAXED,
                             __HIP_MEMORY_SCOPE_AGENT) < epoch)
      __builtin_amdgcn_s_sleep(1);
  }
  __syncthreads();
}

__global__ __launch_bounds__(256) void k0_prep(
    const float* __restrict__ aiw, const float* __restrict__ aib,
    const float* __restrict__ aow, const float* __restrict__ aob,
    const float* __restrict__ outw, const float* __restrict__ lng,
    const float* __restrict__ lnb, char* __restrict__ ws) {
  float* Gm = (float*)(ws + OFF_G);
  float* Nm = (float*)(ws + OFF_NM);
  float* m0 = (float*)(ws + OFF_M0);
  float* n0 = (float*)(ws + OFF_N0);
  float* sc = (float*)(ws + OFF_SC);
  const int blk = blockIdx.x, tid = threadIdx.x;
  if (blk == 512) {
    float* hb = (float*)(ws + OFF_HB);
    int* fl = (int*)(ws + OFF_FLG);
    for (int i = tid; i < NBAT*HID; i += 256) hb[i] = 0.f;           // h0 slot 0
    for (int i = tid; i < 2*NGRP*GBLK*FLS; i += 256) fl[i] = 0;      // flags (replay-safe)
    for (int l = tid; l < HID; l += 256) {
      float s = 0.f;
      for (int i = 0; i < HID; i++) s += aib[i] * aiw[(size_t)(HID + i)*HID + l];
      m0[l] = s;  // Wk^T bq
    }
    for (int j = tid; j < HID; j += 256) {
      float s = aob[j];
      for (int i = 0; i < HID; i++) s += aow[(size_t)j*HID + i] * aib[2*HID + i];
      n0[j] = s;  // aow*bv + aob
    }
    __shared__ float red[256];
    float a = 0.f, b = 0.f;
    for (int l = tid; l < HID; l += 256) { a += outw[l]*lng[l]; b += outw[l]*lnb[l]; }
    red[tid] = a; __syncthreads();
    for (int st = 128; st; st >>= 1) { if (tid < st) red[tid] += red[tid + st]; __syncthreads(); }
    if (tid == 0) sc[0] = red[0];
    __syncthreads();
    red[tid] = b; __syncthreads();
    for (int st = 128; st; st >>= 1) { if (tid < st) red[tid] += red[tid + st]; __syncthreads(); }
    if (tid == 0) sc[1] = red[0];
    return;
  }
  const bool isG = blk < 256;
  const int tb = isG ? blk : blk - 256;
  const int r0 = (tb >> 4) * 32, c0 = (tb & 15) * 32;
  __shared__ float sa[32][33], sb[32][33];
  float acc[4] = {0.f, 0.f, 0.f, 0.f};
  const int tr = tid >> 3, tc = (tid & 7) * 4;
  for (int i0 = 0; i0 < HID; i0 += 32) {
    __syncthreads();
    if (isG) {  // G[l][k] = sum_i Wk[i][l]*Wq[i][k]
      for (int j = 0; j < 4; j++) sa[tr][tc + j] = aiw[(size_t)(HID + i0 + tr)*HID + r0 + tc + j];
      for (int j = 0; j < 4; j++) sb[tr][tc + j] = aiw[(size_t)(i0 + tr)*HID + c0 + tc + j];
    } else {    // N[j][l] = sum_i aow[j][i]*Wv[i][l]
      for (int j = 0; j < 4; j++) sa[tr][tc + j] = aow[(size_t)(r0 + tr)*HID + i0 + tc + j];
      for (int j = 0; j < 4; j++) sb[tr][tc + j] = aiw[(size_t)(2*HID + i0 + tr)*HID + c0 + tc + j];
    }
    __syncthreads();
    if (isG) {
      for (int i = 0; i < 32; i++) {
        float a = sa[i][tr];
        for (int j = 0; j < 4; j++) acc[j] += a * sb[i][tc + j];
      }
    } else {
      for (int i = 0; i < 32; i++) {
        float a = sa[tr][i];
        for (int j = 0; j < 4; j++) acc[j] += a * sb[i][tc + j];
      }
    }
  }
  float* dst = isG ? Gm : Nm;
  for (int j = 0; j < 4; j++) dst[(size_t)(r0 + tr)*HID + c0 + tc + j] = acc[j];
}

// z = Whh_slice * h + x*wih + bias, 4x4 reg tiles, K split over 8 chunks
#define CELL_Z_COMPUTE()                                                          \
  {                                                                               \
    float acc[4][4];                                                              \
    _Pragma("unroll") for (int a = 0; a < 4; a++)                                 \
      _Pragma("unroll") for (int b = 0; b < 4; b++) acc[a][b] = 0.f;              \
    const int p0 = kc * 32;                                                       \
    _Pragma("unroll 2") for (int p = p0; p < p0 + 32; p++) {                      \
      float2 w0 = *(const float2*)&s_w[rg*4+0][2*p];                              \
      float2 w1 = *(const float2*)&s_w[rg*4+1][2*p];                              \
      float2 w2 = *(const float2*)&s_w[rg*4+2][2*p];                              \
      float2 w3 = *(const float2*)&s_w[rg*4+3][2*p];                              \
      float2 h0 = *(const float2*)&s_h[bg*4+0][2*p];                              \
      float2 h1 = *(const float2*)&s_h[bg*4+1][2*p];                              \
      float2 h2 = *(const float2*)&s_h[bg*4+2][2*p];                              \
      float2 h3 = *(const float2*)&s_h[bg*4+3][2*p];                              \
      acc[0][0] += w0.x*h0.x + w0.y*h0.y; acc[0][1] += w0.x*h1.x + w0.y*h1.y;     \
      acc[0][2] += w0.x*h2.x + w0.y*h2.y; acc[0][3] += w0.x*h3.x + w0.y*h3.y;     \
      acc[1][0] += w1.x*h0.x + w1.y*h0.y; acc[1][1] += w1.x*h1.x + w1.y*h1.y;     \
      acc[1][2] += w1.x*h2.x + w1.y*h2.y; acc[1][3] += w1.x*h3.x + w1.y*h3.y;     \
      acc[2][0] += w2.x*h0.x + w2.y*h0.y; acc[2][1] += w2.x*h1.x + w2.y*h1.y;     \
      acc[2][2] += w2.x*h2.x + w2.y*h2.y; acc[2][3] += w2.x*h3.x + w2.y*h3.y;     \
      acc[3][0] += w3.x*h0.x + w3.y*h0.y; acc[3][1] += w3.x*h1.x + w3.y*h1.y;     \
      acc[3][2] += w3.x*h2.x + w3.y*h2.y; acc[3][3] += w3.x*h3.x + w3.y*h3.y;     \
    }                                                                             \
    _Pragma("unroll") for (int a = 0; a < 4; a++)                                 \
      _Pragma("unroll") for (int b = 0; b < 4; b++)                               \
        s_part[kc*512 + (rg*4+a)*GBAT + bg*4 + b] = acc[a][b];                    \
  }                                                                               \
  __syncthreads();                                                                \
  for (int o = tid; o < NR*GBAT; o += 256) {                                      \
    float s = 0.f;                                                                \
    _Pragma("unroll") for (int c = 0; c < 8; c++) s += s_part[c*512 + o];         \
    int r = o >> 4, bb = o & 15;                                                  \
    s_z[o] = s + s_x[bb]*s_wih[r] + s_bias[r];                                    \
  }                                                                               \
  __syncthreads();

// stage 16 batches x 512 h (f32) into LDS via agent-scope 8B loads
#define STAGE_GROUP(dstLDS, srcPTR)                                               \
  {                                                                               \
    const unsigned long long* _s = (const unsigned long long*)(srcPTR);           \
    for (int i = tid; i < GBAT*HID/2; i += 256) {                                 \
      union { unsigned long long u; float f[2]; } cv; cv.u = ldg8(_s + i);        \
      int bb = i >> 8, kk = (i & 255) * 2;                                        \
      dstLDS[bb][kk] = cv.f[0]; dstLDS[bb][kk+1] = cv.f[1];                       \
    }                                                                             \
  }

__global__ __launch_bounds__(256) void k1_enc(
    const float* __restrict__ xin, const float* __restrict__ wih,
    const float* __restrict__ whh, const float* __restrict__ bih,
    const float* __restrict__ bhh, char* __restrict__ ws) {
  const int bk = blockIdx.x, tid = threadIdx.x;
  const int g = bk >> 6, jb = bk & 63;
  const int hs = jb * NH, b0 = g * GBAT;
  float* hbuf = (float*)(ws + OFF_HB);
  float* cbuf = (float*)(ws + OFF_CB);
  __hip_bfloat16* eo = (__hip_bfloat16*)(ws + OFF_EO);
  int* fl = (int*)(ws + OFF_FLG) + g * GBLK * FLS;

  __shared__ float s_w[NR][LDP];
  __shared__ float s_h[GBAT][LDP];
  __shared__ float s_part[8*512];
  __shared__ float s_z[NR*GBAT];
  __shared__ float s_c[GBAT][NH];
  __shared__ float s_x[GBAT];
  __shared__ float s_wih[NR], s_bias[NR];

  for (int r = 0; r < NR; r++) {
    int grow = (r >> 3)*HID + hs + (r & 7);
    for (int k = tid; k < HID; k += 256) s_w[r][k] = whh[(size_t)grow*HID + k];
  }
  if (tid < NR) {
    int grow = (tid >> 3)*HID + hs + (tid & 7);
    s_wih[tid] = wih[grow];
    s_bias[tid] = bih[grow] + bhh[grow];
  }
  for (int i = tid; i < GBAT*NH; i += 256) s_c[i >> 3][i & 7] = 0.f;

  const int rg = tid & 7, bg = (tid >> 3) & 3, kc = tid >> 5;
  int epoch = 0;
  for (int t = 0; t < SEQE; t++) {
    STAGE_GROUP(s_h, hbuf + (size_t)(t & 1)*NBAT*HID + (size_t)b0*HID)
    if (tid < GBAT) s_x[tid] = xin[(size_t)(b0 + tid)*SEQE + t];
    __syncthreads();
    CELL_Z_COMPUTE()
    if (tid < GBAT*NH) {
      int bb = tid >> 3, jj = tid & 7;
      float zi = s_z[(jj)*GBAT + bb];
      float zf = s_z[(8+jj)*GBAT + bb];
      float zg = s_z[(16+jj)*GBAT + bb];
      float zo = s_z[(24+jj)*GBAT + bb];
      float c = s_c[bb][jj];
      c = sigm(zf)*c + sigm(zi)*tanhf(zg);
      float hv = sigm(zo)*tanhf(c);
      s_c[bb][jj] = c;
      stg(&hbuf[(size_t)((t+1)&1)*NBAT*HID + (size_t)(b0+bb)*HID + hs + jj], hv);
      eo[((size_t)(b0+bb)*SEQE + t)*HID + hs + jj] = __float2bfloat16(hv);
    }
    gbar(fl, jb, epoch);
  }
  if (tid < GBAT*NH) {
    int bb = tid >> 3, jj = tid & 7;
    cbuf[(size_t)(b0+bb)*HID + hs + jj] = s_c[bb][jj];
  }
}

__global__ __launch_bounds__(256) void k2_dec(
    const float* __restrict__ xin, const float* __restrict__ wih,
    const float* __restrict__ whh, const float* __restrict__ bih,
    const float* __restrict__ bhh, const float* __restrict__ lng,
    const float* __restrict__ lnb, const float* __restrict__ outw,
    const float* __restrict__ outb, char* __restrict__ ws,
    float* __restrict__ dout) {
  const int bk = blockIdx.x, tid = threadIdx.x;
  const int g = bk >> 6, jb = bk & 63;
  const int hs = jb * NH, b0 = g * GBAT;
  float* hbuf = (float*)(ws + OFF_HB);
  float* cbuf = (float*)(ws + OFF_CB);
  float* xcur = (float*)(ws + OFF_XC);
  float* htil = (float*)(ws + OFF_HT);
  float* ebp  = (float*)(ws + OFF_EBP);
  float* md   = (float*)(ws + OFF_MD);
  float* ebc  = (float*)(ws + OFF_EBC);
  float* lns  = (float*)(ws + OFF_LNS);
  const float* Gm  = (const float*)(ws + OFF_G);
  const float* Nm  = (const float*)(ws + OFF_NM);
  const float* m0v = (const float*)(ws + OFF_M0);
  const float* n0v = (const float*)(ws + OFF_N0);
  const float* scv = (const float*)(ws + OFF_SC);
  const __hip_bfloat16* eo = (const __hip_bfloat16*)(ws + OFF_EO);
  int* fl = (int*)(ws + OFF_FLG) + (NGRP + g) * GBLK * FLS;

  __shared__ float s_w[NR][LDP];
  __shared__ float s_h[GBAT][LDP];
  __shared__ float s_part[8*512];
  __shared__ float s_G[NH][HID];
  __shared__ float s_N[NH][HID];
  __shared__ float s_z[NR*GBAT];
  __shared__ float s_c[GBAT][NH];
  __shared__ float s_hown[GBAT][NH];
  __shared__ float s_x[GBAT];
  __shared__ float s_wih[NR], s_bias[NR];
  __shared__ float s_wg[NH], s_m0[NH], s_n0[NH];
  __shared__ float s_ht[HID];
  __shared__ float s_scores[128];
  __shared__ float s_sc2[256];
  __shared__ float s_red[256];

  for (int r = 0; r < NR; r++) {
    int grow = (r >> 3)*HID + hs + (r & 7);
    for (int k = tid; k < HID; k += 256) s_w[r][k] = whh[(size_t)grow*HID + k];
  }
  for (int i = tid; i < NH*HID; i += 256) {
    int r = i >> 9, k = i & 511;
    s_G[r][k] = Gm[(size_t)(hs + r)*HID + k];
    s_N[r][k] = Nm[(size_t)(hs + r)*HID + k];
  }
  if (tid < NR) {
    int grow = (tid >> 3)*HID + hs + (tid & 7);
    s_wih[tid] = wih[grow];
    s_bias[tid] = bih[grow] + bhh[grow];
  }
  if (tid < NH) {
    s_wg[tid] = outw[hs + tid] * lng[hs + tid];
    s_m0[tid] = m0v[hs + tid];
    s_n0[tid] = n0v[hs + tid];
  }
  for (int i = tid; i < GBAT*NH; i += 256) {
    int bb = i >> 3, jj = i & 7;
    s_c[bb][jj] = cbuf[(size_t)(b0+bb)*HID + hs + jj];
  }
  const float Swg = scv[0], Swb = scv[1], ob0 = outb[0];

  const int rg = tid & 7, bg = (tid >> 3) & 3, kc = tid >> 5;
  const int l8 = tid >> 5, kq = tid & 31;
  int epoch = 0;
  for (int t = 0; t < SEQD; t++) {
    // ---------- P1: LSTM cell ----------
    STAGE_GROUP(s_h, hbuf + (size_t)(t & 1)*NBAT*HID + (size_t)b0*HID)
    if (tid < GBAT) s_x[tid] = (t == 0) ? xin[(size_t)(b0 + tid)*SEQD] : ldg1(&xcur[b0 + tid]);
    __syncthreads();
    CELL_Z_COMPUTE()
    if (tid < GBAT*NH) {
      int bb = tid >> 3, jj = tid & 7;
      float zi = s_z[(jj)*GBAT + bb];
      float zf = s_z[(8+jj)*GBAT + bb];
      float zg = s_z[(16+jj)*GBAT + bb];
      float zo = s_z[(24+jj)*GBAT + bb];
      float c = s_c[bb][jj];
      c = sigm(zf)*c + sigm(zi)*tanhf(zg);
      float hv = sigm(zo)*tanhf(c);
      s_c[bb][jj] = c;
      s_hown[bb][jj] = hv;
      stg(&hbuf[(size_t)((t+1)&1)*NBAT*HID + (size_t)(b0+bb)*HID + hs + jj], hv);
    }
    gbar(fl, jb, epoch);  // B1
    // ---------- P2: htilde = G_slice*h_new + m0 ----------
    STAGE_GROUP(s_h, hbuf + (size_t)((t+1) & 1)*NBAT*HID + (size_t)b0*HID)
    __syncthreads();
    {
      float pacc[GBAT];
      #pragma unroll
      for (int b = 0; b < GBAT; b++) pacc[b] = 0.f;
      const float2* Gr = (const float2*)&s_G[l8][0];
      for (int kk2 = 0; kk2 < 8; kk2++) {
        int p = kk2*32 + kq;
        float2 gv = Gr[p];
        #pragma unroll
        for (int b = 0; b < GBAT; b++) {
          float2 hv2 = *(const float2*)&s_h[b][2*p];
          pacc[b] += gv.x*hv2.x + gv.y*hv2.y;
        }
      }
      #pragma unroll
      for (int b = 0; b < GBAT; b++) s_part[(l8*32 + kq)*GBAT + b] = pacc[b];
    }
    __syncthreads();
    if (tid < NH*GBAT) {
      int l = tid >> 4, b = tid & 15;
      float s = s_m0[l];
      for (int q = 0; q < 32; q++) s += s_part[(l*32 + q)*GBAT + b];
      stg(&htil[(size_t)(b0+b)*HID + hs + l], s);
    }
    gbar(fl, jb, epoch);  // B2
    // ---------- P3: scores + local softmax + ebar partial ----------
    {
      const int bb = jb >> 2, sc = jb & 3;
      const int batch = b0 + bb;
      for (int i = tid; i < HID; i += 256) s_ht[i] = ldg1(&htil[(size_t)batch*HID + i]);
      __syncthreads();
      const int sidx = tid >> 1, half = tid & 1;
      const uint4* ep = (const uint4*)(eo + ((size_t)batch*SEQE + sc*128 + sidx)*HID + half*256);
      float acc = 0.f;
      const int lb = half * 256;
      #pragma unroll 4
      for (int it = 0; it < 32; it++) {
        uint4 u = ep[it];
        int l = lb + it*8;
        acc += bf2f(u.x & 0xffffu)*s_ht[l+0] + bf2f(u.x >> 16)*s_ht[l+1]
             + bf2f(u.y & 0xffffu)*s_ht[l+2] + bf2f(u.y >> 16)*s_ht[l+3]
             + bf2f(u.z & 0xffffu)*s_ht[l+4] + bf2f(u.z >> 16)*s_ht[l+5]
             + bf2f(u.w & 0xffffu)*s_ht[l+6] + bf2f(u.w >> 16)*s_ht[l+7];
      }
      s_sc2[tid] = acc;
      __syncthreads();
      float lg = -1e30f;
      if (tid < 128) { lg = (s_sc2[tid*2] + s_sc2[tid*2+1]) * SCALE; s_scores[tid] = lg; }
      s_red[tid] = lg;
      __syncthreads();
      for (int st = 128; st > 0; st >>= 1) {
        if (tid < st) s_red[tid] = fmaxf(s_red[tid], s_red[tid + st]);
        __syncthreads();
      }
      const float ml = s_red[0];
      __syncthreads();
      float pv = 0.f;
      if (tid < 128) { pv = __expf(s_scores[tid] - ml); s_scores[tid] = pv; }
      s_red[tid] = pv;
      __syncthreads();
      for (int st = 128; st > 0; st >>= 1) {
        if (tid < st) s_red[tid] += s_red[tid + st];
        __syncthreads();
      }
      const float dl = s_red[0];
      float a0 = 0.f, a1 = 0.f;
      const uint32_t* ep2 = (const uint32_t*)(eo + ((size_t)batch*SEQE + sc*128)*HID);
      for (int s = 0; s < 128; s++) {
        float p = s_scores[s];
        uint32_t u = ep2[(size_t)s*(HID/2) + tid];
        a0 += p * bf2f(u & 0xffffu);
        a1 += p * bf2f(u >> 16);
      }
      float* dst = ebp + (size_t)(batch*4 + sc)*HID + 2*tid;
      stg(dst, a0); stg(dst + 1, a1);
      if (tid == 0) { stg(&md[(batch*4 + sc)*2], ml); stg(&md[(batch*4 + sc)*2 + 1], dl); }
    }
    gbar(fl, jb, epoch);  // B3
    // ---------- P4: combine ebar across 4 Se-chunks ----------
    {
      const int bb = jb >> 2, lc = jb & 3;
      const int batch = b0 + bb;
      if (tid < 128) {
        float mm0 = ldg1(&md[batch*8+0]), dd0 = ldg1(&md[batch*8+1]);
        float mm1 = ldg1(&md[batch*8+2]), dd1 = ldg1(&md[batch*8+3]);
        float mm2 = ldg1(&md[batch*8+4]), dd2 = ldg1(&md[batch*8+5]);
        float mm3 = ldg1(&md[batch*8+6]), dd3 = ldg1(&md[batch*8+7]);
        float M = fmaxf(fmaxf(mm0, mm1), fmaxf(mm2, mm3));
        float w0 = __expf(mm0 - M), w1 = __expf(mm1 - M);
        float w2 = __expf(mm2 - M), w3 = __expf(mm3 - M);
        float inv = 1.f / (w0*dd0 + w1*dd1 + w2*dd2 + w3*dd3);
        int l = lc*128 + tid;
        float v = w0*ldg1(&ebp[(size_t)(batch*4+0)*HID + l])
                + w1*ldg1(&ebp[(size_t)(batch*4+1)*HID + l])
                + w2*ldg1(&ebp[(size_t)(batch*4+2)*HID + l])
                + w3*ldg1(&ebp[(size_t)(batch*4+3)*HID + l]);
        stg(&ebc[(size_t)batch*HID + l], v * inv);
      }
    }
    gbar(fl, jb, epoch);  // B4
    // ---------- P5: ctx = N_slice*ebar + n0; y = ctx + h; LN/out partials ----------
    STAGE_GROUP(s_h, ebc + (size_t)b0*HID)
    __syncthreads();
    {
      float pacc[GBAT];
      #pragma unroll
      for (int b = 0; b < GBAT; b++) pacc[b] = 0.f;
      const float2* Nr = (const float2*)&s_N[l8][0];
      for (int kk2 = 0; kk2 < 8; kk2++) {
        int p = kk2*32 + kq;
        float2 nv = Nr[p];
        #pragma unroll
        for (int b = 0; b < GBAT; b++) {
          float2 hv2 = *(const float2*)&s_h[b][2*p];
          pacc[b] += nv.x*hv2.x + nv.y*hv2.y;
        }
      }
      #pragma unroll
      for (int b = 0; b < GBAT; b++) s_part[(l8*32 + kq)*GBAT + b] = pacc[b];
    }
    __syncthreads();
    if (tid < NH*GBAT) {
      int l = tid >> 4, b = tid & 15;
      float s = s_n0[l];
      for (int q = 0; q < 32; q++) s += s_part[(l*32 + q)*GBAT + b];
      float y = s + s_hown[b][l];
      s_z[l*GBAT + b] = y;
    }
    __syncthreads();
    if (tid < GBAT) {
      float sy = 0.f, sy2 = 0.f, sg = 0.f;
      for (int l = 0; l < NH; l++) {
        float y = s_z[l*GBAT + tid];
        sy += y; sy2 += y*y; sg += s_wg[l]*y;
      }
      float* pp = lns + (((size_t)g*GBLK + jb)*GBAT + tid)*4;
      stg(pp, sy); stg(pp+1, sy2); stg(pp+2, sg);
    }
    gbar(fl, jb, epoch);  // B5
    // ---------- P6: per-batch LN finalize + out + feedback ----------
    if (jb < GBAT) {
      const int batch = b0 + jb;
      if (tid < 64) {
        const float* pp = lns + (((size_t)g*GBLK + tid)*GBAT + jb)*4;
        float sy = ldg1(pp), sy2 = ldg1(pp+1), sg = ldg1(pp+2);
        for (int off = 32; off > 0; off >>= 1) {
          sy  += __shfl_down(sy, off);
          sy2 += __shfl_down(sy2, off);
          sg  += __shfl_down(sg, off);
        }
        if (tid == 0) {
          float mu = sy * (1.f/HID);
          float var = sy2 * (1.f/HID) - mu*mu;
          float rs = rsqrtf(var + 1e-5f);
          float o = rs*(sg - mu*Swg) + Swb + ob0;
          dout[(size_t)batch*SEQD + t] = o;
          stg(&xcur[batch], o);
        }
      }
    }
    gbar(fl, jb, epoch);  // B6
  }
}

extern "C" void kernel_launch(void* const* d_in, const int* in_sizes, int n_in,
                              void* d_out, int out_size, void* d_ws, size_t ws_size,
                              hipStream_t stream) {
  const float* enc_in = (const float*)d_in[0];
  const float* dec_in = (const float*)d_in[1];
  const float* ewih = (const float*)d_in[2];
  const float* ewhh = (const float*)d_in[3];
  const float* ebih = (const float*)d_in[4];
  const float* ebhh = (const float*)d_in[5];
  const float* dwih = (const float*)d_in[6];
  const float* dwhh = (const float*)d_in[7];
  const float* dbih = (const float*)d_in[8];
  const float* dbhh = (const float*)d_in[9];
  const float* aiw  = (const float*)d_in[10];
  const float* aib  = (const float*)d_in[11];
  const float* aow  = (const float*)d_in[12];
  const float* aob  = (const float*)d_in[13];
  const float* lng  = (const float*)d_in[14];
  const float* lnb  = (const float*)d_in[15];
  const float* outw = (const float*)d_in[16];
  const float* outb = (const float*)d_in[17];
  char* ws = (char*)d_ws;
  k0_prep<<<513, 256, 0, stream>>>(aiw, aib, aow, aob, outw, lng, lnb, ws);
  k1_enc<<<256, 256, 0, stream>>>(enc_in, ewih, ewhh, ebih, ebhh, ws);
  k2_dec<<<256, 256, 0, stream>>>(dec_in, dwih, dwhh, dbih, dbhh,
                                  lng, lnb, outw, outb, ws, (float*)d_out);
}

// Round 3
// 7356.642 us; speedup vs baseline: 9.1583x; 1.5324x over previous
//
#include <hip/hip_runtime.h>
#include <hip/hip_bf16.h>
#include <stdint.h>

// Seq2Seq w/ attention, MI355X. R3: MFMA cell (split-bf16), frag-order weights,
// no-max softmax, 5 barriers/dec-step, redundant LN-finalize.
//  K0 : G=Wq^T Wk, N=aow*Wv (f32), bias folds, Swg/Swb; zero h0/flags.
//  K0b: convert G,N to bf16 MFMA B-fragment order (Gb,Nb).
//  K1 : encoder, 4 grp x 64 blk; z = MFMA(h_frags, Whh_frags); 1 barrier/step.
//  K2 : decoder, 5 barriers/step: B1 h -> B2 htilde -> B3 score/ebar partials ->
//       B4 ebar combine -> B5 LN partials -> (local) out+x.

#define HID 512
#define NBAT 64
#define SEQE 512
#define SEQD 128
#define NGRP 4
#define GBAT 16
#define GBLK 64
#define NH 8
#define SCALE 0.04419417382415922f
#define FLS 16

typedef __attribute__((ext_vector_type(8))) short bf16x8;
typedef __attribute__((ext_vector_type(4))) float f32x4;
#define MFMA_B16 __builtin_amdgcn_mfma_f32_16x16x32_bf16

static constexpr size_t OFF_G   = 0;
static constexpr size_t OFF_NM  = OFF_G  + (size_t)HID*HID*4;
static constexpr size_t OFF_M0  = OFF_NM + (size_t)HID*HID*4;
static constexpr size_t OFF_N0  = OFF_M0 + 2048;
static constexpr size_t OFF_SC  = OFF_N0 + 2048;                    // Swg, Swb
static constexpr size_t OFF_HB  = OFF_SC + 256;                     // h dbuf [2][B][H] u32(hi,lo)
static constexpr size_t OFF_CB  = OFF_HB + (size_t)2*NBAT*HID*4;    // c handoff f32
static constexpr size_t OFF_XC  = OFF_CB + (size_t)NBAT*HID*4;      // (unused)
static constexpr size_t OFF_HT  = OFF_XC + 256;                     // htilde [B][H] f32
static constexpr size_t OFF_EBP = OFF_HT + (size_t)NBAT*HID*4;      // ebar num partials [B][4][H]
static constexpr size_t OFF_MD  = OFF_EBP + (size_t)NBAT*4*HID*4;   // den [B][4]
static constexpr size_t OFF_EBC = OFF_MD + (size_t)NBAT*4*4;        // ebar combined [B][H]
static constexpr size_t OFF_LNS = OFF_EBC + (size_t)NBAT*HID*4;     // [G][64][16][4]
static constexpr size_t OFF_FLG = OFF_LNS + (size_t)NGRP*GBLK*GBAT*4*4;
static constexpr size_t OFF_EO  = ((OFF_FLG + (size_t)2*NGRP*GBLK*FLS*4 + 255) & ~(size_t)255);
static constexpr size_t OFF_GB  = OFF_EO + (size_t)NBAT*SEQE*HID*2; // G frag bf16 [64][16][64][8]
static constexpr size_t OFF_NB  = OFF_GB + (size_t)GBLK*16*64*8*2;  // N frag bf16

__device__ __forceinline__ float bf2f(uint32_t u) {
  union { float f; uint32_t i; } x; x.i = u << 16; return x.f;
}
__device__ __forceinline__ unsigned short bfbits(float f) {
  __hip_bfloat16 h = __float2bfloat16(f);
  return *(unsigned short*)&h;
}
__device__ __forceinline__ uint32_t splitbf(float f) {
  unsigned short hi = bfbits(f);
  union { uint32_t u; float ff; } c; c.u = (uint32_t)hi << 16;
  unsigned short lo = bfbits(f - c.ff);
  return (uint32_t)hi | ((uint32_t)lo << 16);
}
__device__ __forceinline__ float sigm(float x) { return 1.f / (1.f + __expf(-x)); }

__device__ __forceinline__ void stg(float* p, float v) {
  __hip_atomic_store(p, v, __ATOMIC_RELAXED, __HIP_MEMORY_SCOPE_AGENT);
}
__device__ __forceinline__ void stgu(uint32_t* p, uint32_t v) {
  __hip_atomic_store(p, v, __ATOMIC_RELAXED, __HIP_MEMORY_SCOPE_AGENT);
}
__device__ __forceinline__ float ldg1(const float* p) {
  return __hip_atomic_load((float*)p, __ATOMIC_RELAXED, __HIP_MEMORY_SCOPE_AGENT);
}
__device__ __forceinline__ unsigned long long ldg8(const void* p) {
  return __hip_atomic_load((unsigned long long*)p, __ATOMIC_RELAXED, __HIP_MEMORY_SCOPE_AGENT);
}

// fence-free 64-block barrier (R2-verified)
__device__ __forceinline__ void gbar(int* fl, int jb, int& epoch) {
  __syncthreads();
  epoch++;
  if (threadIdx.x == 0)
    __hip_atomic_store(&fl[jb * FLS], epoch, __ATOMIC_RELAXED, __HIP_MEMORY_SCOPE_AGENT);
  if (threadIdx.x < GBLK) {
    while (__hip_atomic_load(&fl[threadIdx.x * FLS], __ATOMIC_RELAXED,
                             __HIP_MEMORY_SCOPE_AGENT) < epoch)
      __builtin_amdgcn_s_sleep(1);
  }
  __syncthreads();
}

__global__ __launch_bounds__(256) void k0_prep(
    const float* __restrict__ aiw, const float* __restrict__ aib,
    const float* __restrict__ aow, const float* __restrict__ aob,
    const float* __restrict__ outw, const float* __restrict__ lng,
    const float* __restrict__ lnb, char* __restrict__ ws) {
  float* Gm = (float*)(ws + OFF_G);
  float* Nm = (float*)(ws + OFF_NM);
  float* m0 = (float*)(ws + OFF_M0);
  float* n0 = (float*)(ws + OFF_N0);
  float* sc = (float*)(ws + OFF_SC);
  const int blk = blockIdx.x, tid = threadIdx.x;
  if (blk == 512) {
    uint32_t* hb = (uint32_t*)(ws + OFF_HB);
    int* fl = (int*)(ws + OFF_FLG);
    for (int i = tid; i < NBAT*HID; i += 256) hb[i] = 0u;            // h0 (bf16 pair 0,0)
    for (int i = tid; i < 2*NGRP*GBLK*FLS; i += 256) fl[i] = 0;
    for (int l = tid; l < HID; l += 256) {
      float s = 0.f;
      for (int i = 0; i < HID; i++) s += aib[i] * aiw[(size_t)(HID + i)*HID + l];
      m0[l] = s;
    }
    for (int j = tid; j < HID; j += 256) {
      float s = aob[j];
      for (int i = 0; i < HID; i++) s += aow[(size_t)j*HID + i] * aib[2*HID + i];
      n0[j] = s;
    }
    __shared__ float red[256];
    float a = 0.f, b = 0.f;
    for (int l = tid; l < HID; l += 256) { a += outw[l]*lng[l]; b += outw[l]*lnb[l]; }
    red[tid] = a; __syncthreads();
    for (int st = 128; st; st >>= 1) { if (tid < st) red[tid] += red[tid + st]; __syncthreads(); }
    if (tid == 0) sc[0] = red[0];
    __syncthreads();
    red[tid] = b; __syncthreads();
    for (int st = 128; st; st >>= 1) { if (tid < st) red[tid] += red[tid + st]; __syncthreads(); }
    if (tid == 0) sc[1] = red[0];
    return;
  }
  const bool isG = blk < 256;
  const int tb = isG ? blk : blk - 256;
  const int r0 = (tb >> 4) * 32, c0 = (tb & 15) * 32;
  __shared__ float sa[32][33], sb[32][33];
  float acc[4] = {0.f, 0.f, 0.f, 0.f};
  const int tr = tid >> 3, tc = (tid & 7) * 4;
  for (int i0 = 0; i0 < HID; i0 += 32) {
    __syncthreads();
    if (isG) {
      for (int j = 0; j < 4; j++) sa[tr][tc + j] = aiw[(size_t)(HID + i0 + tr)*HID + r0 + tc + j];
      for (int j = 0; j < 4; j++) sb[tr][tc + j] = aiw[(size_t)(i0 + tr)*HID + c0 + tc + j];
    } else {
      for (int j = 0; j < 4; j++) sa[tr][tc + j] = aow[(size_t)(r0 + tr)*HID + i0 + tc + j];
      for (int j = 0; j < 4; j++) sb[tr][tc + j] = aiw[(size_t)(2*HID + i0 + tr)*HID + c0 + tc + j];
    }
    __syncthreads();
    if (isG) {
      for (int i = 0; i < 32; i++) {
        float a = sa[i][tr];
        for (int j = 0; j < 4; j++) acc[j] += a * sb[i][tc + j];
      }
    } else {
      for (int i = 0; i < 32; i++) {
        float a = sa[tr][i];
        for (int j = 0; j < 4; j++) acc[j] += a * sb[i][tc + j];
      }
    }
  }
  float* dst = isG ? Gm : Nm;
  for (int j = 0; j < 4; j++) dst[(size_t)(r0 + tr)*HID + c0 + tc + j] = acc[j];
}

// G,N f32 -> bf16 B-fragment order: [jb][ks][lane][8]; cols 8..15 zeroed.
__global__ __launch_bounds__(256) void k0b_frag(char* __restrict__ ws) {
  const float* Gm = (const float*)(ws + OFF_G);
  const float* Nm = (const float*)(ws + OFF_NM);
  unsigned short* Gb = (unsigned short*)(ws + OFF_GB);
  unsigned short* Nb = (unsigned short*)(ws + OFF_NB);
  const int jb = blockIdx.x, tid = threadIdx.x;
  for (int slot = tid; slot < 16*64; slot += 256) {
    int ks = slot >> 6, l = slot & 63;
    int col = l & 15, ko = ks*32 + ((l >> 4) << 3);
    unsigned short hg[8] __attribute__((aligned(16)));
    unsigned short hn[8] __attribute__((aligned(16)));
    for (int j = 0; j < 8; j++) {
      float gv = 0.f, nv = 0.f;
      if (col < 8) {
        gv = Gm[(size_t)(jb*8 + col)*HID + ko + j];
        nv = Nm[(size_t)(jb*8 + col)*HID + ko + j];
      }
      hg[j] = bfbits(gv); hn[j] = bfbits(nv);
    }
    *(uint4*)(Gb + ((size_t)(jb*16 + ks)*64 + l)*8) = *(uint4*)hg;
    *(uint4*)(Nb + ((size_t)(jb*16 + ks)*64 + l)*8) = *(uint4*)hn;
  }
}

// stage packed h (hi,lo u32) -> s_hh / s_hl bf16 LDS, batch-major [16][520]
#define STAGE_H(srcPTR)                                                               \
  {                                                                                   \
    const unsigned long long* _s = (const unsigned long long*)(srcPTR);               \
    for (int i = tid; i < GBAT*HID/2; i += 256) {                                     \
      unsigned long long u = ldg8(_s + i);                                            \
      int bb = i >> 8, kk = (i & 255) * 2;                                            \
      *(uint32_t*)&s_hh[bb][kk] = (uint32_t)(u & 0xffffu) | (((uint32_t)(u >> 32) & 0xffffu) << 16); \
      *(uint32_t*)&s_hl[bb][kk] = ((uint32_t)(u >> 16) & 0xffffu) | ((uint32_t)(u >> 48) << 16);     \
    }                                                                                 \
  }

// split-bf16 Whh frag init into LDS (once per block)
#define WFRAG_INIT()                                                                  \
  for (int slot = tid; slot < 2*16*64; slot += 256) {                                 \
    int T = slot >> 10, ks = (slot >> 6) & 15, l = slot & 63;                         \
    int rloc = T*16 + (l & 15);                                                       \
    int grow = (rloc >> 3)*HID + hs + (rloc & 7);                                     \
    int ko = ks*32 + ((l >> 4) << 3);                                                 \
    const float* wp = &whh[(size_t)grow*HID + ko];                                    \
    unsigned short hi[8] __attribute__((aligned(16)));                                \
    unsigned short lo[8] __attribute__((aligned(16)));                                \
    for (int j = 0; j < 8; j++) {                                                     \
      uint32_t u = splitbf(wp[j]);                                                    \
      hi[j] = (unsigned short)u; lo[j] = (unsigned short)(u >> 16);                   \
    }                                                                                 \
    *(uint4*)&s_wf[T][ks][l][0] = *(uint4*)hi;                                        \
    *(uint4*)&s_wl[T][ks][l][0] = *(uint4*)lo;                                        \
  }

// cell MFMA: z[b][r] tiles; wave wv does ksteps wv*4..+3, both tiles, 3 split terms
#define CELL_MFMA()                                                                   \
  {                                                                                   \
    f32x4 acc0 = {0.f,0.f,0.f,0.f}, acc1 = {0.f,0.f,0.f,0.f};                         \
    _Pragma("unroll") for (int kq = 0; kq < 4; kq++) {                                \
      const int ks = wv*4 + kq;                                                       \
      const int ko = ks*32 + (oc << 3);                                               \
      bf16x8 ahi = *(const bf16x8*)&s_hh[lm][ko];                                     \
      bf16x8 alo = *(const bf16x8*)&s_hl[lm][ko];                                     \
      bf16x8 b0h = *(const bf16x8*)&s_wf[0][ks][l][0];                                \
      bf16x8 b0l = *(const bf16x8*)&s_wl[0][ks][l][0];                                \
      bf16x8 b1h = *(const bf16x8*)&s_wf[1][ks][l][0];                                \
      bf16x8 b1l = *(const bf16x8*)&s_wl[1][ks][l][0];                                \
      acc0 = MFMA_B16(ahi, b0h, acc0, 0, 0, 0);                                       \
      acc0 = MFMA_B16(alo, b0h, acc0, 0, 0, 0);                                       \
      acc0 = MFMA_B16(ahi, b0l, acc0, 0, 0, 0);                                       \
      acc1 = MFMA_B16(ahi, b1h, acc1, 0, 0, 0);                                       \
      acc1 = MFMA_B16(alo, b1h, acc1, 0, 0, 0);                                       \
      acc1 = MFMA_B16(ahi, b1l, acc1, 0, 0, 0);                                       \
    }                                                                                 \
    _Pragma("unroll") for (int q = 0; q < 4; q++) {                                   \
      int idx = (oc*4 + q)*16 + lm;                                                   \
      s_pacc[wv][0][idx] = acc0[q];                                                   \
      s_pacc[wv][1][idx] = acc1[q];                                                   \
    }                                                                                 \
  }                                                                                   \
  __syncthreads();

__global__ __launch_bounds__(256) void k1_enc(
    const float* __restrict__ xin, const float* __restrict__ wih,
    const float* __restrict__ whh, const float* __restrict__ bih,
    const float* __restrict__ bhh, char* __restrict__ ws) {
  const int bk = blockIdx.x, tid = threadIdx.x;
  const int g = bk >> 6, jb = bk & 63;
  const int hs = jb * NH, b0 = g * GBAT;
  uint32_t* hbuf = (uint32_t*)(ws + OFF_HB);
  float* cbuf = (float*)(ws + OFF_CB);
  unsigned short* eo = (unsigned short*)(ws + OFF_EO);
  int* fl = (int*)(ws + OFF_FLG) + g * GBLK * FLS;

  __shared__ unsigned short s_wf[2][16][64][8];
  __shared__ unsigned short s_wl[2][16][64][8];
  __shared__ unsigned short s_hh[GBAT][520];
  __shared__ unsigned short s_hl[GBAT][520];
  __shared__ float s_pacc[4][2][256];
  __shared__ float s_c[GBAT][NH];
  __shared__ float s_x[GBAT];
  __shared__ float s_wih[32], s_bias[32];

  WFRAG_INIT()
  if (tid < 32) {
    int grow = (tid >> 3)*HID + hs + (tid & 7);
    s_wih[tid] = wih[grow];
    s_bias[tid] = bih[grow] + bhh[grow];
  }
  for (int i = tid; i < GBAT*NH; i += 256) s_c[i >> 3][i & 7] = 0.f;

  const int l = tid & 63, wv = tid >> 6;
  const int lm = l & 15, oc = l >> 4;
  int epoch = 0;
  for (int t = 0; t < SEQE; t++) {
    STAGE_H(hbuf + (size_t)(t & 1)*NBAT*HID + (size_t)b0*HID)
    if (tid < GBAT) s_x[tid] = xin[(size_t)(b0 + tid)*SEQE + t];
    __syncthreads();
    CELL_MFMA()
    if (tid < 128) {
      int b = tid >> 3, j = tid & 7;
      float x = s_x[b];
      float zi = s_pacc[0][0][b*16+j]   + s_pacc[1][0][b*16+j]   + s_pacc[2][0][b*16+j]   + s_pacc[3][0][b*16+j]
               + x*s_wih[j] + s_bias[j];
      float zf = s_pacc[0][0][b*16+8+j] + s_pacc[1][0][b*16+8+j] + s_pacc[2][0][b*16+8+j] + s_pacc[3][0][b*16+8+j]
               + x*s_wih[8+j] + s_bias[8+j];
      float zg = s_pacc[0][1][b*16+j]   + s_pacc[1][1][b*16+j]   + s_pacc[2][1][b*16+j]   + s_pacc[3][1][b*16+j]
               + x*s_wih[16+j] + s_bias[16+j];
      float zo = s_pacc[0][1][b*16+8+j] + s_pacc[1][1][b*16+8+j] + s_pacc[2][1][b*16+8+j] + s_pacc[3][1][b*16+8+j]
               + x*s_wih[24+j] + s_bias[24+j];
      float c = s_c[b][j];
      c = sigm(zf)*c + sigm(zi)*tanhf(zg);
      float hv = sigm(zo)*tanhf(c);
      s_c[b][j] = c;
      uint32_t pk = splitbf(hv);
      stgu(&hbuf[(size_t)((t+1)&1)*NBAT*HID + (size_t)(b0+b)*HID + hs + j], pk);
      eo[((size_t)(b0+b)*SEQE + t)*HID + hs + j] = (unsigned short)(pk & 0xffffu);
    }
    gbar(fl, jb, epoch);
  }
  if (tid < GBAT*NH)
    cbuf[(size_t)(b0 + (tid >> 3))*HID + hs + (tid & 7)] = s_c[tid >> 3][tid & 7];
}

__global__ __launch_bounds__(256) void k2_dec(
    const float* __restrict__ xin, const float* __restrict__ wih,
    const float* __restrict__ whh, const float* __restrict__ bih,
    const float* __restrict__ bhh, const float* __restrict__ lng,
    const float* __restrict__ lnb, const float* __restrict__ outw,
    const float* __restrict__ outb, char* __restrict__ ws,
    float* __restrict__ dout) {
  const int bk = blockIdx.x, tid = threadIdx.x;
  const int g = bk >> 6, jb = bk & 63;
  const int hs = jb * NH, b0 = g * GBAT;
  uint32_t* hbuf = (uint32_t*)(ws + OFF_HB);
  float* cbuf = (float*)(ws + OFF_CB);
  float* htil = (float*)(ws + OFF_HT);
  float* ebp  = (float*)(ws + OFF_EBP);
  float* md   = (float*)(ws + OFF_MD);
  float* ebc  = (float*)(ws + OFF_EBC);
  float* lns  = (float*)(ws + OFF_LNS);
  const float* m0v = (const float*)(ws + OFF_M0);
  const float* n0v = (const float*)(ws + OFF_N0);
  const float* scv = (const float*)(ws + OFF_SC);
  const unsigned short* eo = (const unsigned short*)(ws + OFF_EO);
  const unsigned short* Gb = (const unsigned short*)(ws + OFF_GB);
  const unsigned short* Nb = (const unsigned short*)(ws + OFF_NB);
  int* fl = (int*)(ws + OFF_FLG) + (NGRP + g) * GBLK * FLS;

  __shared__ unsigned short s_wf[2][16][64][8];
  __shared__ unsigned short s_wl[2][16][64][8];
  __shared__ unsigned short s_hh[GBAT][520];
  __shared__ unsigned short s_hl[GBAT][520];
  __shared__ unsigned short s_eb[GBAT][520];
  __shared__ float s_pacc[4][2][256];
  __shared__ float s_c[GBAT][NH];
  __shared__ float s_hown[GBAT][NH];
  __shared__ float s_x[GBAT];
  __shared__ float s_wih[32], s_bias[32];
  __shared__ float s_m0[NH], s_n0[NH], s_wg[NH];
  __shared__ float s_ht[HID];
  __shared__ float s_scores[128];
  __shared__ float s_sc2[256];
  __shared__ float s_red[256];

  WFRAG_INIT()
  if (tid < 32) {
    int grow = (tid >> 3)*HID + hs + (tid & 7);
    s_wih[tid] = wih[grow];
    s_bias[tid] = bih[grow] + bhh[grow];
  }
  if (tid < NH) {
    s_m0[tid] = m0v[hs + tid];
    s_n0[tid] = n0v[hs + tid];
    s_wg[tid] = outw[hs + tid] * lng[hs + tid];
  }
  for (int i = tid; i < GBAT*NH; i += 256)
    s_c[i >> 3][i & 7] = cbuf[(size_t)(b0 + (i >> 3))*HID + hs + (i & 7)];
  const float Swg = scv[0], Swb = scv[1], ob0 = outb[0];

  const int l = tid & 63, wv = tid >> 6;
  const int lm = l & 15, oc = l >> 4;

  // pre-loop: stage h_e (slot 0) and x0
  STAGE_H(hbuf + (size_t)b0*HID)
  if (tid < GBAT) s_x[tid] = xin[(size_t)(b0 + tid)*SEQD];
  __syncthreads();

  int epoch = 0;
  for (int t = 0; t < SEQD; t++) {
    // ---- P1: LSTM cell ----
    CELL_MFMA()
    if (tid < 128) {
      int b = tid >> 3, j = tid & 7;
      float x = s_x[b];
      float zi = s_pacc[0][0][b*16+j]   + s_pacc[1][0][b*16+j]   + s_pacc[2][0][b*16+j]   + s_pacc[3][0][b*16+j]
               + x*s_wih[j] + s_bias[j];
      float zf = s_pacc[0][0][b*16+8+j] + s_pacc[1][0][b*16+8+j] + s_pacc[2][0][b*16+8+j] + s_pacc[3][0][b*16+8+j]
               + x*s_wih[8+j] + s_bias[8+j];
      float zg = s_pacc[0][1][b*16+j]   + s_pacc[1][1][b*16+j]   + s_pacc[2][1][b*16+j]   + s_pacc[3][1][b*16+j]
               + x*s_wih[16+j] + s_bias[16+j];
      float zo = s_pacc[0][1][b*16+8+j] + s_pacc[1][1][b*16+8+j] + s_pacc[2][1][b*16+8+j] + s_pacc[3][1][b*16+8+j]
               + x*s_wih[24+j] + s_bias[24+j];
      float c = s_c[b][j];
      c = sigm(zf)*c + sigm(zi)*tanhf(zg);
      float hv = sigm(zo)*tanhf(c);
      s_c[b][j] = c;
      s_hown[b][j] = hv;
      stgu(&hbuf[(size_t)((t+1)&1)*NBAT*HID + (size_t)(b0+b)*HID + hs + j], splitbf(hv));
    }
    gbar(fl, jb, epoch);  // B1
    // ---- P2: stage h_new; htilde = G*h_new + m0 ----
    STAGE_H(hbuf + (size_t)((t+1)&1)*NBAT*HID + (size_t)b0*HID)
    __syncthreads();
    {
      f32x4 aG = {0.f,0.f,0.f,0.f};
      #pragma unroll
      for (int kq = 0; kq < 4; kq++) {
        const int ks = wv*4 + kq;
        bf16x8 ahi = *(const bf16x8*)&s_hh[lm][ks*32 + (oc << 3)];
        bf16x8 gb = *(const bf16x8*)(Gb + ((size_t)(jb*16 + ks)*64 + l)*8);
        aG = MFMA_B16(ahi, gb, aG, 0, 0, 0);
      }
      #pragma unroll
      for (int q = 0; q < 4; q++) s_pacc[wv][0][(oc*4 + q)*16 + lm] = aG[q];
    }
    __syncthreads();
    if (tid < 128) {
      int b = tid >> 3, gr = tid & 7;
      float v = s_m0[gr] + s_pacc[0][0][b*16+gr] + s_pacc[1][0][b*16+gr]
              + s_pacc[2][0][b*16+gr] + s_pacc[3][0][b*16+gr];
      stg(&htil[(size_t)(b0+b)*HID + hs + gr], v);
    }
    gbar(fl, jb, epoch);  // B2
    // ---- P3: scores + exp (no max) + num/den partials ----
    {
      const int bb = jb >> 2, scq = jb & 3;
      const int batch = b0 + bb;
      for (int i = tid; i < HID; i += 256) s_ht[i] = ldg1(&htil[(size_t)batch*HID + i]);
      __syncthreads();
      const int sidx = tid >> 1, half = tid & 1;
      const uint4* ep = (const uint4*)(eo + ((size_t)batch*SEQE + scq*128 + sidx)*HID + half*256);
      float acc = 0.f;
      const int lb = half * 256;
      #pragma unroll 4
      for (int it = 0; it < 32; it++) {
        uint4 u = ep[it];
        int ll = lb + it*8;
        acc += bf2f(u.x & 0xffffu)*s_ht[ll+0] + bf2f(u.x >> 16)*s_ht[ll+1]
             + bf2f(u.y & 0xffffu)*s_ht[ll+2] + bf2f(u.y >> 16)*s_ht[ll+3]
             + bf2f(u.z & 0xffffu)*s_ht[ll+4] + bf2f(u.z >> 16)*s_ht[ll+5]
             + bf2f(u.w & 0xffffu)*s_ht[ll+6] + bf2f(u.w >> 16)*s_ht[ll+7];
      }
      s_sc2[tid] = acc;
      __syncthreads();
      float pv = 0.f;
      if (tid < 128) { pv = __expf((s_sc2[tid*2] + s_sc2[tid*2+1]) * SCALE); s_scores[tid] = pv; }
      s_red[tid] = pv;
      __syncthreads();
      for (int st = 128; st > 0; st >>= 1) {
        if (tid < st) s_red[tid] += s_red[tid + st];
        __syncthreads();
      }
      if (tid == 0) stg(&md[batch*4 + scq], s_red[0]);
      float a0 = 0.f, a1 = 0.f;
      const uint32_t* ep2 = (const uint32_t*)(eo + ((size_t)batch*SEQE + scq*128)*HID);
      for (int s = 0; s < 128; s++) {
        float p = s_scores[s];
        uint32_t u = ep2[(size_t)s*(HID/2) + tid];
        a0 += p * bf2f(u & 0xffffu);
        a1 += p * bf2f(u >> 16);
      }
      float* dst = ebp + (size_t)(batch*4 + scq)*HID + 2*tid;
      stg(dst, a0); stg(dst + 1, a1);
    }
    gbar(fl, jb, epoch);  // B3
    // ---- P4: combine num/den -> ebar ----
    if (tid < 128) {
      const int bb = jb >> 2, lc = jb & 3;
      const int batch = b0 + bb;
      float den = ldg1(&md[batch*4]) + ldg1(&md[batch*4+1])
                + ldg1(&md[batch*4+2]) + ldg1(&md[batch*4+3]);
      float inv = 1.f / den;
      int lcl = lc*128 + tid;
      float v = ldg1(&ebp[(size_t)(batch*4+0)*HID + lcl])
              + ldg1(&ebp[(size_t)(batch*4+1)*HID + lcl])
              + ldg1(&ebp[(size_t)(batch*4+2)*HID + lcl])
              + ldg1(&ebp[(size_t)(batch*4+3)*HID + lcl]);
      stg(&ebc[(size_t)batch*HID + lcl], v * inv);
    }
    gbar(fl, jb, epoch);  // B4
    // ---- P5: ctx = N*ebar + n0; y; LN partials ----
    {
      const unsigned long long* _s = (const unsigned long long*)(ebc + (size_t)b0*HID);
      for (int i = tid; i < GBAT*HID/2; i += 256) {
        unsigned long long u = ldg8(_s + i);
        union { unsigned long long uu; float f[2]; } cv; cv.uu = u;
        int bb = i >> 8, kk = (i & 255) * 2;
        *(uint32_t*)&s_eb[bb][kk] = (uint32_t)bfbits(cv.f[0]) | ((uint32_t)bfbits(cv.f[1]) << 16);
      }
    }
    __syncthreads();
    {
      f32x4 aN = {0.f,0.f,0.f,0.f};
      #pragma unroll
      for (int kq = 0; kq < 4; kq++) {
        const int ks = wv*4 + kq;
        bf16x8 ahi = *(const bf16x8*)&s_eb[lm][ks*32 + (oc << 3)];
        bf16x8 nb = *(const bf16x8*)(Nb + ((size_t)(jb*16 + ks)*64 + l)*8);
        aN = MFMA_B16(ahi, nb, aN, 0, 0, 0);
      }
      #pragma unroll
      for (int q = 0; q < 4; q++) s_pacc[wv][0][(oc*4 + q)*16 + lm] = aN[q];
    }
    __syncthreads();
    if (tid < 128) {
      int b = tid >> 3, nr = tid & 7;
      float ctx = s_n0[nr] + s_pacc[0][0][b*16+nr] + s_pacc[1][0][b*16+nr]
                + s_pacc[2][0][b*16+nr] + s_pacc[3][0][b*16+nr];
      float y = ctx + s_hown[b][nr];
      float sy = y, sy2 = y*y, sg = s_wg[nr]*y;
      for (int off = 4; off; off >>= 1) {
        sy  += __shfl_down(sy, off, 8);
        sy2 += __shfl_down(sy2, off, 8);
        sg  += __shfl_down(sg, off, 8);
      }
      if (nr == 0) {
        float* pp = lns + (((size_t)g*GBLK + jb)*GBAT + b)*4;
        stg(pp, sy); stg(pp+1, sy2); stg(pp+2, sg);
      }
    }
    gbar(fl, jb, epoch);  // B5
    // ---- P6 (local, redundant): LN finalize + out + x feedback ----
    {
      int b = tid >> 4, part = tid & 15;
      float sy = 0.f, sy2 = 0.f, sg = 0.f;
      for (int r = 0; r < 4; r++) {
        const float* pp = lns + (((size_t)g*GBLK + part*4 + r)*GBAT + b)*4;
        sy += ldg1(pp); sy2 += ldg1(pp+1); sg += ldg1(pp+2);
      }
      for (int off = 8; off; off >>= 1) {
        sy  += __shfl_down(sy, off, 16);
        sy2 += __shfl_down(sy2, off, 16);
        sg  += __shfl_down(sg, off, 16);
      }
      if (part == 0) {
        float mu = sy * (1.f/HID);
        float var = sy2 * (1.f/HID) - mu*mu;
        float rs = rsqrtf(var + 1e-5f);
        float o = rs*(sg - mu*Swg) + Swb + ob0;
        s_x[b] = o;
        if (jb == b) dout[(size_t)(b0+b)*SEQD + t] = o;
      }
    }
    __syncthreads();
  }
}

extern "C" void kernel_launch(void* const* d_in, const int* in_sizes, int n_in,
                              void* d_out, int out_size, void* d_ws, size_t ws_size,
                              hipStream_t stream) {
  const float* enc_in = (const float*)d_in[0];
  const float* dec_in = (const float*)d_in[1];
  const float* ewih = (const float*)d_in[2];
  const float* ewhh = (const float*)d_in[3];
  const float* ebih = (const float*)d_in[4];
  const float* ebhh = (const float*)d_in[5];
  const float* dwih = (const float*)d_in[6];
  const float* dwhh = (const float*)d_in[7];
  const float* dbih = (const float*)d_in[8];
  const float* dbhh = (const float*)d_in[9];
  const float* aiw  = (const float*)d_in[10];
  const float* aib  = (const float*)d_in[11];
  const float* aow  = (const float*)d_in[12];
  const float* aob  = (const float*)d_in[13];
  const float* lng  = (const float*)d_in[14];
  const float* lnb  = (const float*)d_in[15];
  const float* outw = (const float*)d_in[16];
  const float* outb = (const float*)d_in[17];
  char* ws = (char*)d_ws;
  k0_prep<<<513, 256, 0, stream>>>(aiw, aib, aow, aob, outw, lng, lnb, ws);
  k0b_frag<<<64, 256, 0, stream>>>(ws);
  k1_enc<<<256, 256, 0, stream>>>(enc_in, ewih, ewhh, ebih, ebhh, ws);
  k2_dec<<<256, 256, 0, stream>>>(dec_in, dwih, dwhh, dbih, dbhh,
                                  lng, lnb, outw, outb, ws, (float*)d_out);
}

// Round 5
// 4144.682 us; speedup vs baseline: 16.2556x; 1.7750x over previous
//
#include <hip/hip_runtime.h>
#include <hip/hip_bf16.h>
#include <stdint.h>

// Seq2Seq w/ attention, MI355X. R5 = R4 with corrected MFMA D-fragment extraction.
// Convention (verified by R3 cell): lane l loads A[row=l&15][k=(l>>4)*8+j];
// lane l reg q holds D[row=(l>>4)*4+q][col=l&15], col = B-col.
//  K0 : G fold, N=aow*Wv, m0/n0/wqb/Swg/Swb/bqbk; zero h0/flags.
//  K0b: MFMA B-fragments of G2=Wq^T Wk and N (bf16).
//  K1 : encoder. MFMA cell (split-bf16), 1 barrier/step, writes eo bf16.
//  K0c: K~[b][s][l] = G2*e + wqb (overwrites eo), V~t[b][l][s] = N*e, kb[b][s].
//  K2 : decoder. B1 h -> P2 scores/PV MFMA partials -> B2 -> P3 LN/out -> B3 x.

#define HID 512
#define NBAT 64
#define SEQE 512
#define SEQD 128
#define NGRP 4
#define GBAT 16
#define GBLK 64
#define NH 8
#define SCALE 0.04419417382415922f
#define FLS 16

typedef __attribute__((ext_vector_type(8))) short bf16x8;
typedef __attribute__((ext_vector_type(4))) float f32x4;
#define MFMA_B16 __builtin_amdgcn_mfma_f32_16x16x32_bf16

static constexpr size_t OFF_G   = 0;
static constexpr size_t OFF_NM  = OFF_G  + (size_t)HID*HID*4;
static constexpr size_t OFF_M0  = OFF_NM + (size_t)HID*HID*4;
static constexpr size_t OFF_N0  = OFF_M0 + 2048;
static constexpr size_t OFF_WQB = OFF_N0 + 2048;
static constexpr size_t OFF_SC  = OFF_WQB + 2048;                   // Swg, Swb, bqbk
static constexpr size_t OFF_HB  = OFF_SC + 256;                     // h dbuf [2][B][H] u32(hi,lo)
static constexpr size_t OFF_CB  = OFF_HB + (size_t)2*NBAT*HID*4;    // c handoff f32
static constexpr size_t OFF_XC  = OFF_CB + (size_t)NBAT*HID*4;      // x feedback [B]
static constexpr size_t OFF_EBP = OFF_XC + 256;                     // PV partials [B][4][H] f32
static constexpr size_t OFF_MD  = OFF_EBP + (size_t)NBAT*4*HID*4;   // den partials [B][4]
static constexpr size_t OFF_KB  = OFF_MD + (size_t)NBAT*4*4;        // kb [B][Se] f32
static constexpr size_t OFF_FLG = OFF_KB + (size_t)NBAT*SEQE*4;
static constexpr size_t OFF_BFK = ((OFF_FLG + (size_t)2*NGRP*GBLK*FLS*4 + 255) & ~(size_t)255);
static constexpr size_t OFF_BFV = OFF_BFK + (size_t)16*32*64*8*2;   // 512KB each
static constexpr size_t OFF_EO  = OFF_BFV + (size_t)16*32*64*8*2;   // eo then K~ [B][Se][H] bf16
static constexpr size_t OFF_VT  = OFF_EO + (size_t)NBAT*SEQE*HID*2; // V~t [B][H][Se] bf16

__device__ __forceinline__ float bf2f(uint32_t u) {
  union { float f; uint32_t i; } x; x.i = u << 16; return x.f;
}
__device__ __forceinline__ unsigned short bfbits(float f) {
  __hip_bfloat16 h = __float2bfloat16(f);
  return *(unsigned short*)&h;
}
__device__ __forceinline__ uint32_t splitbf(float f) {
  unsigned short hi = bfbits(f);
  union { uint32_t u; float ff; } c; c.u = (uint32_t)hi << 16;
  unsigned short lo = bfbits(f - c.ff);
  return (uint32_t)hi | ((uint32_t)lo << 16);
}
__device__ __forceinline__ float sigm(float x) { return 1.f / (1.f + __expf(-x)); }

__device__ __forceinline__ void stg(float* p, float v) {
  __hip_atomic_store(p, v, __ATOMIC_RELAXED, __HIP_MEMORY_SCOPE_AGENT);
}
__device__ __forceinline__ void stgu(uint32_t* p, uint32_t v) {
  __hip_atomic_store(p, v, __ATOMIC_RELAXED, __HIP_MEMORY_SCOPE_AGENT);
}
__device__ __forceinline__ float ldg1(const float* p) {
  return __hip_atomic_load((float*)p, __ATOMIC_RELAXED, __HIP_MEMORY_SCOPE_AGENT);
}
__device__ __forceinline__ unsigned long long ldg8(const void* p) {
  return __hip_atomic_load((unsigned long long*)p, __ATOMIC_RELAXED, __HIP_MEMORY_SCOPE_AGENT);
}

// fence-free 64-block barrier (R2/R3-verified)
__device__ __forceinline__ void gbar(int* fl, int jb, int& epoch) {
  __syncthreads();
  epoch++;
  if (threadIdx.x == 0)
    __hip_atomic_store(&fl[jb * FLS], epoch, __ATOMIC_RELAXED, __HIP_MEMORY_SCOPE_AGENT);
  if (threadIdx.x < GBLK) {
    while (__hip_atomic_load(&fl[threadIdx.x * FLS], __ATOMIC_RELAXED,
                             __HIP_MEMORY_SCOPE_AGENT) < epoch)
      __builtin_amdgcn_s_sleep(1);
  }
  __syncthreads();
}

__global__ __launch_bounds__(256) void k0_prep(
    const float* __restrict__ aiw, const float* __restrict__ aib,
    const float* __restrict__ aow, const float* __restrict__ aob,
    const float* __restrict__ outw, const float* __restrict__ lng,
    const float* __restrict__ lnb, char* __restrict__ ws) {
  float* Gm = (float*)(ws + OFF_G);
  float* Nm = (float*)(ws + OFF_NM);
  float* m0 = (float*)(ws + OFF_M0);
  float* n0 = (float*)(ws + OFF_N0);
  float* wqb = (float*)(ws + OFF_WQB);
  float* sc = (float*)(ws + OFF_SC);
  const int blk = blockIdx.x, tid = threadIdx.x;
  if (blk == 512) {
    uint32_t* hb = (uint32_t*)(ws + OFF_HB);
    int* fl = (int*)(ws + OFF_FLG);
    for (int i = tid; i < NBAT*HID; i += 256) hb[i] = 0u;            // h0 slot 0
    for (int i = tid; i < 2*NGRP*GBLK*FLS; i += 256) fl[i] = 0;      // replay-safe
    for (int l = tid; l < HID; l += 256) {
      float s = 0.f;
      for (int i = 0; i < HID; i++) s += aib[i] * aiw[(size_t)(HID + i)*HID + l];
      m0[l] = s;  // Wk^T bq
    }
    for (int l = tid; l < HID; l += 256) {
      float s = 0.f;
      for (int i = 0; i < HID; i++) s += aiw[(size_t)i*HID + l] * aib[HID + i];
      wqb[l] = s;  // Wq^T bk
    }
    for (int j = tid; j < HID; j += 256) {
      float s = aob[j];
      for (int i = 0; i < HID; i++) s += aow[(size_t)j*HID + i] * aib[2*HID + i];
      n0[j] = s;  // aow*bv + aob
    }
    __shared__ float red[256];
    float a = 0.f, b = 0.f, d = 0.f;
    for (int l = tid; l < HID; l += 256) {
      a += outw[l]*lng[l]; b += outw[l]*lnb[l]; d += aib[l]*aib[HID + l];
    }
    red[tid] = a; __syncthreads();
    for (int st = 128; st; st >>= 1) { if (tid < st) red[tid] += red[tid + st]; __syncthreads(); }
    if (tid == 0) sc[0] = red[0];
    __syncthreads();
    red[tid] = b; __syncthreads();
    for (int st = 128; st; st >>= 1) { if (tid < st) red[tid] += red[tid + st]; __syncthreads(); }
    if (tid == 0) sc[1] = red[0];
    __syncthreads();
    red[tid] = d; __syncthreads();
    for (int st = 128; st; st >>= 1) { if (tid < st) red[tid] += red[tid + st]; __syncthreads(); }
    if (tid == 0) sc[2] = red[0];  // bq.bk
    return;
  }
  const bool isG = blk < 256;
  const int tb = isG ? blk : blk - 256;
  const int r0 = (tb >> 4) * 32, c0 = (tb & 15) * 32;
  __shared__ float sa[32][33], sb[32][33];
  float acc[4] = {0.f, 0.f, 0.f, 0.f};
  const int tr = tid >> 3, tc = (tid & 7) * 4;
  for (int i0 = 0; i0 < HID; i0 += 32) {
    __syncthreads();
    if (isG) {  // Gm[l][k] = sum_i Wk[i][l]*Wq[i][k]  (= G2[k][l], G2 = Wq^T Wk)
      for (int j = 0; j < 4; j++) sa[tr][tc + j] = aiw[(size_t)(HID + i0 + tr)*HID + r0 + tc + j];
      for (int j = 0; j < 4; j++) sb[tr][tc + j] = aiw[(size_t)(i0 + tr)*HID + c0 + tc + j];
    } else {    // N[j][l] = sum_i aow[j][i]*Wv[i][l]
      for (int j = 0; j < 4; j++) sa[tr][tc + j] = aow[(size_t)(r0 + tr)*HID + i0 + tc + j];
      for (int j = 0; j < 4; j++) sb[tr][tc + j] = aiw[(size_t)(2*HID + i0 + tr)*HID + c0 + tc + j];
    }
    __syncthreads();
    if (isG) {
      for (int i = 0; i < 32; i++) {
        float a = sa[i][tr];
        for (int j = 0; j < 4; j++) acc[j] += a * sb[i][tc + j];
      }
    } else {
      for (int i = 0; i < 32; i++) {
        float a = sa[tr][i];
        for (int j = 0; j < 4; j++) acc[j] += a * sb[i][tc + j];
      }
    }
  }
  float* dst = isG ? Gm : Nm;
  for (int j = 0; j < 4; j++) dst[(size_t)(r0 + tr)*HID + c0 + tc + j] = acc[j];
}

// B-fragments: Bfk[ks][lt][l][j] = G2[lt*16+(l&15)][ks*32+(l>>4)*8+j] (G2[a][b]=Gm[b][a]);
// Bfv[ks][lt][l][j] = Nm[lt*16+(l&15)][ks*32+(l>>4)*8+j].
__global__ __launch_bounds__(256) void k0b_frag(char* __restrict__ ws) {
  const float* Gm = (const float*)(ws + OFF_G);
  const float* Nm = (const float*)(ws + OFF_NM);
  unsigned short* Bfk = (unsigned short*)(ws + OFF_BFK);
  unsigned short* Bfv = (unsigned short*)(ws + OFF_BFV);
  const int idx0 = blockIdx.x * 256 + threadIdx.x;
  for (int idx = idx0; idx < 16*32*64; idx += 64*256) {
    int ks = idx >> 11, lt = (idx >> 6) & 31, l = idx & 63;
    int lcol = lt*16 + (l & 15), krow = ks*32 + ((l >> 4) << 3);
    unsigned short hk[8] __attribute__((aligned(16)));
    unsigned short hv[8] __attribute__((aligned(16)));
    for (int j = 0; j < 8; j++) {
      hk[j] = bfbits(Gm[(size_t)(krow + j)*HID + lcol]);
      hv[j] = bfbits(Nm[(size_t)lcol*HID + krow + j]);
    }
    *(uint4*)(Bfk + (size_t)idx*8) = *(uint4*)hk;
    *(uint4*)(Bfv + (size_t)idx*8) = *(uint4*)hv;
  }
}

// stage packed h (hi,lo u32): two-phase (all loads in flight, then LDS writes)
#define STAGE_H(srcPTR)                                                               \
  {                                                                                   \
    const unsigned long long* _s = (const unsigned long long*)(srcPTR);               \
    unsigned long long _t[16];                                                        \
    _Pragma("unroll") for (int r = 0; r < 16; r++) _t[r] = ldg8(_s + tid + r*256);    \
    _Pragma("unroll") for (int r = 0; r < 16; r++) {                                  \
      int i = tid + r*256;                                                            \
      int bb_ = i >> 8, kk = (i & 255) * 2;                                           \
      unsigned long long u = _t[r];                                                   \
      *(uint32_t*)&s_hh[bb_][kk] = (uint32_t)(u & 0xffffu) | (((uint32_t)(u >> 32) & 0xffffu) << 16); \
      *(uint32_t*)&s_hl[bb_][kk] = ((uint32_t)(u >> 16) & 0xffffu) | ((uint32_t)(u >> 48) << 16);     \
    }                                                                                 \
  }

#define WFRAG_INIT()                                                                  \
  for (int slot = tid; slot < 2*16*64; slot += 256) {                                 \
    int T = slot >> 10, ks = (slot >> 6) & 15, l_ = slot & 63;                        \
    int rloc = T*16 + (l_ & 15);                                                      \
    int grow = (rloc >> 3)*HID + hs + (rloc & 7);                                     \
    int ko = ks*32 + ((l_ >> 4) << 3);                                                \
    const float* wp = &whh[(size_t)grow*HID + ko];                                    \
    unsigned short hi[8] __attribute__((aligned(16)));                                \
    unsigned short lo[8] __attribute__((aligned(16)));                                \
    for (int j = 0; j < 8; j++) {                                                     \
      uint32_t u = splitbf(wp[j]);                                                    \
      hi[j] = (unsigned short)u; lo[j] = (unsigned short)(u >> 16);                   \
    }                                                                                 \
    *(uint4*)&s_wf[T][ks][l_][0] = *(uint4*)hi;                                       \
    *(uint4*)&s_wl[T][ks][l_][0] = *(uint4*)lo;                                       \
  }

#define CELL_MFMA()                                                                   \
  {                                                                                   \
    f32x4 acc0 = {0.f,0.f,0.f,0.f}, acc1 = {0.f,0.f,0.f,0.f};                         \
    _Pragma("unroll") for (int kq = 0; kq < 4; kq++) {                                \
      const int ks = wv*4 + kq;                                                       \
      const int ko = ks*32 + (oc << 3);                                               \
      bf16x8 ahi = *(const bf16x8*)&s_hh[lm][ko];                                     \
      bf16x8 alo = *(const bf16x8*)&s_hl[lm][ko];                                     \
      bf16x8 b0h = *(const bf16x8*)&s_wf[0][ks][l][0];                                \
      bf16x8 b0l = *(const bf16x8*)&s_wl[0][ks][l][0];                                \
      bf16x8 b1h = *(const bf16x8*)&s_wf[1][ks][l][0];                                \
      bf16x8 b1l = *(const bf16x8*)&s_wl[1][ks][l][0];                                \
      acc0 = MFMA_B16(ahi, b0h, acc0, 0, 0, 0);                                       \
      acc0 = MFMA_B16(alo, b0h, acc0, 0, 0, 0);                                       \
      acc0 = MFMA_B16(ahi, b0l, acc0, 0, 0, 0);                                       \
      acc1 = MFMA_B16(ahi, b1h, acc1, 0, 0, 0);                                       \
      acc1 = MFMA_B16(alo, b1h, acc1, 0, 0, 0);                                       \
      acc1 = MFMA_B16(ahi, b1l, acc1, 0, 0, 0);                                       \
    }                                                                                 \
    _Pragma("unroll") for (int q = 0; q < 4; q++) {                                   \
      int idx = (oc*4 + q)*16 + lm;                                                   \
      s_pacc[wv][0][idx] = acc0[q];                                                   \
      s_pacc[wv][1][idx] = acc1[q];                                                   \
    }                                                                                 \
  }                                                                                   \
  __syncthreads();

__global__ __launch_bounds__(256) void k1_enc(
    const float* __restrict__ xin, const float* __restrict__ wih,
    const float* __restrict__ whh, const float* __restrict__ bih,
    const float* __restrict__ bhh, char* __restrict__ ws) {
  const int bk = blockIdx.x, tid = threadIdx.x;
  const int g = bk >> 6, jb = bk & 63;
  const int hs = jb * NH, b0 = g * GBAT;
  uint32_t* hbuf = (uint32_t*)(ws + OFF_HB);
  float* cbuf = (float*)(ws + OFF_CB);
  unsigned short* eo = (unsigned short*)(ws + OFF_EO);
  int* fl = (int*)(ws + OFF_FLG) + g * GBLK * FLS;

  __shared__ __align__(16) unsigned short s_wf[2][16][64][8];
  __shared__ __align__(16) unsigned short s_wl[2][16][64][8];
  __shared__ __align__(16) unsigned short s_hh[GBAT][520];
  __shared__ __align__(16) unsigned short s_hl[GBAT][520];
  __shared__ float s_pacc[4][2][256];
  __shared__ float s_c[GBAT][NH];
  __shared__ float s_x[GBAT];
  __shared__ float s_wih[32], s_bias[32];

  WFRAG_INIT()
  if (tid < 32) {
    int grow = (tid >> 3)*HID + hs + (tid & 7);
    s_wih[tid] = wih[grow];
    s_bias[tid] = bih[grow] + bhh[grow];
  }
  for (int i = tid; i < GBAT*NH; i += 256) s_c[i >> 3][i & 7] = 0.f;

  const int l = tid & 63, wv = tid >> 6;
  const int lm = l & 15, oc = l >> 4;
  int epoch = 0;
  for (int t = 0; t < SEQE; t++) {
    STAGE_H(hbuf + (size_t)(t & 1)*NBAT*HID + (size_t)b0*HID)
    if (tid < GBAT) s_x[tid] = xin[(size_t)(b0 + tid)*SEQE + t];
    __syncthreads();
    CELL_MFMA()
    if (tid < 128) {
      int b = tid >> 3, j = tid & 7;
      float x = s_x[b];
      float zi = s_pacc[0][0][b*16+j]   + s_pacc[1][0][b*16+j]   + s_pacc[2][0][b*16+j]   + s_pacc[3][0][b*16+j]
               + x*s_wih[j] + s_bias[j];
      float zf = s_pacc[0][0][b*16+8+j] + s_pacc[1][0][b*16+8+j] + s_pacc[2][0][b*16+8+j] + s_pacc[3][0][b*16+8+j]
               + x*s_wih[8+j] + s_bias[8+j];
      float zg = s_pacc[0][1][b*16+j]   + s_pacc[1][1][b*16+j]   + s_pacc[2][1][b*16+j]   + s_pacc[3][1][b*16+j]
               + x*s_wih[16+j] + s_bias[16+j];
      float zo = s_pacc[0][1][b*16+8+j] + s_pacc[1][1][b*16+8+j] + s_pacc[2][1][b*16+8+j] + s_pacc[3][1][b*16+8+j]
               + x*s_wih[24+j] + s_bias[24+j];
      float c = s_c[b][j];
      c = sigm(zf)*c + sigm(zi)*tanhf(zg);
      float hv = sigm(zo)*tanhf(c);
      s_c[b][j] = c;
      uint32_t pk = splitbf(hv);
      stgu(&hbuf[(size_t)((t+1)&1)*NBAT*HID + (size_t)(b0+b)*HID + hs + j], pk);
      eo[((size_t)(b0+b)*SEQE + t)*HID + hs + j] = (unsigned short)(pk & 0xffffu);
    }
    gbar(fl, jb, epoch);
  }
  if (tid < GBAT*NH)
    cbuf[(size_t)(b0 + (tid >> 3))*HID + hs + (tid & 7)] = s_c[tid >> 3][tid & 7];
}

// K~ = G2*e + wqb (in-place over eo rows), V~t = N*e (transposed), kb = m0.e + bqbk
// Lane mapping (verified convention): accK{st}[q] = K~[s0+st*16+oc*4+q][lt*16+lm].
__global__ __launch_bounds__(256) void k0c_kv(char* __restrict__ ws) {
  const float* wqb = (const float*)(ws + OFF_WQB);
  const float* m0 = (const float*)(ws + OFF_M0);
  const float* scv = (const float*)(ws + OFF_SC);
  const unsigned short* Bfk = (const unsigned short*)(ws + OFF_BFK);
  const unsigned short* Bfv = (const unsigned short*)(ws + OFF_BFV);
  unsigned short* eoK = (unsigned short*)(ws + OFF_EO);
  unsigned short* Vt = (unsigned short*)(ws + OFF_VT);
  float* kbv = (float*)(ws + OFF_KB);
  const int b = blockIdx.x >> 4, s0 = (blockIdx.x & 15) * 32;
  const int tid = threadIdx.x;
  __shared__ __align__(16) unsigned short s_e[32][520];
  __shared__ float s_kb[32][8];
  {
    const uint4* src = (const uint4*)(eoK + ((size_t)b*SEQE + s0)*HID);
    #pragma unroll
    for (int r = 0; r < 8; r++) {
      int i = tid + r*256;
      uint4 v = src[i];
      int rr = i >> 6, cc = (i & 63)*8;
      *(uint4*)&s_e[rr][cc] = v;
    }
  }
  __syncthreads();
  const int l = tid & 63, wv = tid >> 6, lm = l & 15, oc = l >> 4;
  // kb first (reads s_e before eoK rows get overwritten is irrelevant: s_e is LDS)
  for (int nt = 0; nt < 8; nt++) {
    const int lt = wv*8 + nt;
    f32x4 accK0 = {0,0,0,0}, accK1 = {0,0,0,0}, accV0 = {0,0,0,0}, accV1 = {0,0,0,0};
    #pragma unroll
    for (int ks = 0; ks < 16; ks++) {
      bf16x8 yk = *(const bf16x8*)(Bfk + (((size_t)ks*32 + lt)*64 + l)*8);
      bf16x8 yv = *(const bf16x8*)(Bfv + (((size_t)ks*32 + lt)*64 + l)*8);
      bf16x8 xe0 = *(const bf16x8*)&s_e[lm][ks*32 + oc*8];
      bf16x8 xe1 = *(const bf16x8*)&s_e[16 + lm][ks*32 + oc*8];
      accK0 = MFMA_B16(xe0, yk, accK0, 0,0,0);
      accK1 = MFMA_B16(xe1, yk, accK1, 0,0,0);
      accV0 = MFMA_B16(xe0, yv, accV0, 0,0,0);
      accV1 = MFMA_B16(xe1, yv, accV1, 0,0,0);
    }
    const float wq = wqb[lt*16 + lm];
    #pragma unroll
    for (int st = 0; st < 2; st++) {
      const f32x4& aK = st ? accK1 : accK0;
      const f32x4& aV = st ? accV1 : accV0;
      // K~: s = s0 + st*16 + oc*4 + q (row), l = lt*16 + lm (col) -> scalar stores
      #pragma unroll
      for (int q = 0; q < 4; q++)
        eoK[((size_t)b*SEQE + s0 + st*16 + oc*4 + q)*HID + lt*16 + lm] = bfbits(aK[q] + wq);
      // V~t[b][l][s]: contiguous in q -> u64 pack
      unsigned short pv[4] __attribute__((aligned(8)));
      #pragma unroll
      for (int q = 0; q < 4; q++) pv[q] = bfbits(aV[q]);
      *(unsigned long long*)(Vt + ((size_t)b*HID + lt*16 + lm)*SEQE + s0 + st*16 + oc*4)
          = *(unsigned long long*)pv;
    }
  }
  {
    int s = tid >> 3, kc = tid & 7;
    float acc = 0.f;
    for (int i = 0; i < 64; i++) {
      int k = kc*64 + i;
      acc += bf2f((uint32_t)s_e[s][k]) * m0[k];
    }
    s_kb[s][kc] = acc;
  }
  __syncthreads();
  if (tid < 32) {
    float a = 0.f;
    for (int kc = 0; kc < 8; kc++) a += s_kb[tid][kc];
    kbv[(size_t)b*SEQE + s0 + tid] = a + scv[2];
  }
}

__global__ __launch_bounds__(256) void k2_dec(
    const float* __restrict__ xin, const float* __restrict__ wih,
    const float* __restrict__ whh, const float* __restrict__ bih,
    const float* __restrict__ bhh, const float* __restrict__ lng,
    const float* __restrict__ lnb, const float* __restrict__ outw,
    const float* __restrict__ outb, char* __restrict__ ws,
    float* __restrict__ dout) {
  const int bk = blockIdx.x, tid = threadIdx.x;
  const int g = bk >> 6, jb = bk & 63;
  const int hs = jb * NH, b0 = g * GBAT;
  uint32_t* hbuf = (uint32_t*)(ws + OFF_HB);
  float* cbuf = (float*)(ws + OFF_CB);
  float* xcur = (float*)(ws + OFF_XC);
  float* ebp  = (float*)(ws + OFF_EBP);
  float* md   = (float*)(ws + OFF_MD);
  const float* n0v = (const float*)(ws + OFF_N0);
  const float* scv = (const float*)(ws + OFF_SC);
  const float* kbv = (const float*)(ws + OFF_KB);
  const unsigned short* Kt = (const unsigned short*)(ws + OFF_EO);
  const unsigned short* Vt = (const unsigned short*)(ws + OFF_VT);
  int* fl = (int*)(ws + OFF_FLG) + (NGRP + g) * GBLK * FLS;

  __shared__ __align__(16) unsigned short s_wf[2][16][64][8];
  __shared__ __align__(16) unsigned short s_wl[2][16][64][8];
  __shared__ __align__(16) unsigned short s_hh[GBAT][520];
  __shared__ __align__(16) unsigned short s_hl[GBAT][520];
  __shared__ float s_pacc[4][2][256];
  __shared__ float s_c[GBAT][NH];
  __shared__ float s_x[GBAT];
  __shared__ float s_wih[32], s_bias[32];
  __shared__ float s_scores[128];
  __shared__ __align__(16) uint32_t s_pbf[64];
  __shared__ float s_red[32];
  __shared__ float s_ln[HID], s_n0f[HID];

  WFRAG_INIT()
  if (tid < 32) {
    int grow = (tid >> 3)*HID + hs + (tid & 7);
    s_wih[tid] = wih[grow];
    s_bias[tid] = bih[grow] + bhh[grow];
  }
  for (int i = tid; i < HID; i += 256) {
    s_ln[i] = outw[i] * lng[i];
    s_n0f[i] = n0v[i];
  }
  for (int i = tid; i < GBAT*NH; i += 256)
    s_c[i >> 3][i & 7] = cbuf[(size_t)(b0 + (i >> 3))*HID + hs + (i & 7)];
  const float Swg = scv[0], Swb = scv[1], ob0 = outb[0];

  const int l = tid & 63, wv = tid >> 6;
  const int lm = l & 15, oc = l >> 4;
  const int bb = jb >> 2, scq = jb & 3, batch = b0 + bb;

  STAGE_H(hbuf + (size_t)b0*HID)     // h_e (slot 0)
  if (tid < GBAT) s_x[tid] = xin[(size_t)(b0 + tid)*SEQD];
  __syncthreads();

  int epoch = 0;
  for (int t = 0; t < SEQD; t++) {
    // ---- P1: LSTM cell ----
    CELL_MFMA()
    if (tid < 128) {
      int b = tid >> 3, j = tid & 7;
      float x = s_x[b];
      float zi = s_pacc[0][0][b*16+j]   + s_pacc[1][0][b*16+j]   + s_pacc[2][0][b*16+j]   + s_pacc[3][0][b*16+j]
               + x*s_wih[j] + s_bias[j];
      float zf = s_pacc[0][0][b*16+8+j] + s_pacc[1][0][b*16+8+j] + s_pacc[2][0][b*16+8+j] + s_pacc[3][0][b*16+8+j]
               + x*s_wih[8+j] + s_bias[8+j];
      float zg = s_pacc[0][1][b*16+j]   + s_pacc[1][1][b*16+j]   + s_pacc[2][1][b*16+j]   + s_pacc[3][1][b*16+j]
               + x*s_wih[16+j] + s_bias[16+j];
      float zo = s_pacc[0][1][b*16+8+j] + s_pacc[1][1][b*16+8+j] + s_pacc[2][1][b*16+8+j] + s_pacc[3][1][b*16+8+j]
               + x*s_wih[24+j] + s_bias[24+j];
      float c = s_c[b][j];
      c = sigm(zf)*c + sigm(zi)*tanhf(zg);
      float hv = sigm(zo)*tanhf(c);
      s_c[b][j] = c;
      stgu(&hbuf[(size_t)((t+1)&1)*NBAT*HID + (size_t)(b0+b)*HID + hs + j], splitbf(hv));
    }
    gbar(fl, jb, epoch);  // B1: h_t visible
    // ---- P2: stage h_t; scores + PV MFMA partials for (batch, scq) ----
    STAGE_H(hbuf + (size_t)((t+1)&1)*NBAT*HID + (size_t)b0*HID)
    __syncthreads();
    {
      // scores: wave wv covers s_local = wv*32 .. +32; A = broadcast h -> D[.][col]=score[base+col]
      const unsigned short* kp = Kt + ((size_t)batch*SEQE + scq*128 + wv*32)*HID;
      #pragma unroll
      for (int st = 0; st < 2; st++) {
        f32x4 acc = {0.f,0.f,0.f,0.f};
        #pragma unroll
        for (int ks = 0; ks < 16; ks++) {
          bf16x8 xh = *(const bf16x8*)&s_hh[bb][ks*32 + oc*8];
          bf16x8 yk = *(const bf16x8*)(kp + (size_t)(st*16 + lm)*HID + ks*32 + oc*8);
          acc = MFMA_B16(xh, yk, acc, 0, 0, 0);
        }
        if (oc == 0) s_scores[wv*32 + st*16 + lm] = acc[0];  // lane holds col=lm
      }
    }
    __syncthreads();
    float den_part = 0.f;
    if (tid < 128) {
      float sv = (s_scores[tid] + kbv[(size_t)batch*SEQE + scq*128 + tid]) * SCALE;
      den_part = __expf(sv);
      s_scores[tid] = den_part;
    }
    __syncthreads();
    if (tid < 64)
      s_pbf[tid] = (uint32_t)bfbits(s_scores[2*tid]) | ((uint32_t)bfbits(s_scores[2*tid+1]) << 16);
    if (tid < 128) {
      for (int off = 32; off; off >>= 1) den_part += __shfl_down(den_part, off);
      if ((tid & 63) == 0) s_red[tid >> 6] = den_part;
    }
    __syncthreads();
    if (tid == 0) stg(&md[batch*4 + scq], s_red[0] + s_red[1]);
    {
      // PV: wave wv covers ltiles wv*8 .. +8; A = broadcast p -> D[.][col]=ctxnum[lv0+col]
      const unsigned short* vp = Vt + (size_t)batch*HID*SEQE + (size_t)scq*128;
      #pragma unroll
      for (int n = 0; n < 8; n++) {
        const int lv0 = (wv*8 + n)*16;
        f32x4 acc = {0.f,0.f,0.f,0.f};
        #pragma unroll
        for (int ks = 0; ks < 4; ks++) {
          bf16x8 xp = *(const bf16x8*)((const unsigned short*)s_pbf + ks*32 + oc*8);
          bf16x8 yv = *(const bf16x8*)(vp + (size_t)(lv0 + lm)*SEQE + ks*32 + oc*8);
          acc = MFMA_B16(xp, yv, acc, 0, 0, 0);
        }
        if (oc == 0) stg(&ebp[((size_t)batch*4 + scq)*HID + lv0 + lm], acc[0]);
      }
    }
    gbar(fl, jb, epoch);  // B2: partials visible
    // ---- P3: batch-blocks (jb<16) combine + LN + out + feedback ----
    if (jb < GBAT) {
      const int mb = b0 + jb;
      if (tid < 4) s_red[tid] = ldg1(&md[mb*4 + tid]);
      __syncthreads();
      const float inv = 1.f / (s_red[0] + s_red[1] + s_red[2] + s_red[3]);
      float sy = 0.f, sy2 = 0.f, sg = 0.f;
      #pragma unroll
      for (int u = 0; u < 2; u++) {
        const int lv = tid*2 + u;
        float p0 = ldg1(&ebp[((size_t)mb*4 + 0)*HID + lv]);
        float p1 = ldg1(&ebp[((size_t)mb*4 + 1)*HID + lv]);
        float p2 = ldg1(&ebp[((size_t)mb*4 + 2)*HID + lv]);
        float p3 = ldg1(&ebp[((size_t)mb*4 + 3)*HID + lv]);
        float hval = bf2f((uint32_t)s_hh[jb][lv]) + bf2f((uint32_t)s_hl[jb][lv]);
        float y = (p0 + p1 + p2 + p3)*inv + s_n0f[lv] + hval;
        sy += y; sy2 += y*y; sg += s_ln[lv]*y;
      }
      for (int off = 32; off; off >>= 1) {
        sy += __shfl_down(sy, off); sy2 += __shfl_down(sy2, off); sg += __shfl_down(sg, off);
      }
      if (l == 0) { s_red[8+wv] = sy; s_red[12+wv] = sy2; s_red[16+wv] = sg; }
      __syncthreads();
      if (tid == 0) {
        float Sy  = s_red[8]  + s_red[9]  + s_red[10] + s_red[11];
        float Sy2 = s_red[12] + s_red[13] + s_red[14] + s_red[15];
        float Sg  = s_red[16] + s_red[17] + s_red[18] + s_red[19];
        float mu = Sy * (1.f/HID);
        float var = Sy2 * (1.f/HID) - mu*mu;
        float rs = rsqrtf(var + 1e-5f);
        float o = rs*(Sg - mu*Swg) + Swb + ob0;
        dout[(size_t)mb*SEQD + t] = o;
        stg(&xcur[mb], o);
      }
    }
    gbar(fl, jb, epoch);  // B3: x_t visible
    if (tid < GBAT) s_x[tid] = ldg1(&xcur[b0 + tid]);
  }
}

extern "C" void kernel_launch(void* const* d_in, const int* in_sizes, int n_in,
                              void* d_out, int out_size, void* d_ws, size_t ws_size,
                              hipStream_t stream) {
  const float* enc_in = (const float*)d_in[0];
  const float* dec_in = (const float*)d_in[1];
  const float* ewih = (const float*)d_in[2];
  const float* ewhh = (const float*)d_in[3];
  const float* ebih = (const float*)d_in[4];
  const float* ebhh = (const float*)d_in[5];
  const float* dwih = (const float*)d_in[6];
  const float* dwhh = (const float*)d_in[7];
  const float* dbih = (const float*)d_in[8];
  const float* dbhh = (const float*)d_in[9];
  const float* aiw  = (const float*)d_in[10];
  const float* aib  = (const float*)d_in[11];
  const float* aow  = (const float*)d_in[12];
  const float* aob  = (const float*)d_in[13];
  const float* lng  = (const float*)d_in[14];
  const float* lnb  = (const float*)d_in[15];
  const float* outw = (const float*)d_in[16];
  const float* outb = (const float*)d_in[17];
  char* ws = (char*)d_ws;
  k0_prep<<<513, 256, 0, stream>>>(aiw, aib, aow, aob, outw, lng, lnb, ws);
  k0b_frag<<<64, 256, 0, stream>>>(ws);
  k1_enc<<<256, 256, 0, stream>>>(enc_in, ewih, ewhh, ebih, ebhh, ws);
  k0c_kv<<<1024, 256, 0, stream>>>(ws);
  k2_dec<<<256, 256, 0, stream>>>(dec_in, dwih, dwhh, dbih, dbhh,
                                  lng, lnb, outw, outb, ws, (float*)d_out);
}